// Round 1
// baseline (4183.665 us; speedup 1.0000x reference)
//
#include <hip/hip_runtime.h>
#include <hip/hip_bf16.h>
#include <math.h>

#define B_ 8
#define M_ 1024
#define DM_ 1024
#define H_ 16
#define DH_ 64
#define R_ 32
#define DFF_ 4096
#define NR_ 8192  /* B*M */

// ---------------------------------------------------------------------------
// Fused low-rank QKV: out[b,h,m,e] = (x[b,m,:] @ P[h,:,:]) @ Vw[h,:,:] + bias[h,e]
// grid: (NR_/64, H_), block 256
// ---------------------------------------------------------------------------
__global__ __launch_bounds__(256) void qkv_kernel(
    const float* __restrict__ x, const float* __restrict__ P,
    const float* __restrict__ Vw, const float* __restrict__ bias,
    float* __restrict__ out)
{
    __shared__ float Xs[64][65];
    __shared__ float Ps[64][33];
    __shared__ float Ts[64][33];
    __shared__ float Vs[32][65];
    const int tile = blockIdx.x, h = blockIdx.y, tid = threadIdx.x;
    const int row0 = tile * 64;
    const int col = tid & 31;   // r index
    const int rg  = tid >> 5;   // 0..7 (8 rows each)

    float acc[8];
#pragma unroll
    for (int j = 0; j < 8; ++j) acc[j] = 0.f;

    for (int kc = 0; kc < DM_; kc += 64) {
#pragma unroll
        for (int i = 0; i < 16; ++i) {
            int e = tid + i * 256;
            int r = e >> 6, c = e & 63;
            Xs[r][c] = x[(size_t)(row0 + r) * DM_ + kc + c];
        }
#pragma unroll
        for (int i = 0; i < 8; ++i) {
            int e = tid + i * 256;
            int r = e >> 5, c = e & 31;
            Ps[r][c] = P[(size_t)h * DM_ * R_ + (size_t)(kc + r) * R_ + c];
        }
        __syncthreads();
        for (int kk = 0; kk < 64; ++kk) {
            float pv = Ps[kk][col];
#pragma unroll
            for (int j = 0; j < 8; ++j)
                acc[j] += Xs[rg * 8 + j][kk] * pv;
        }
        __syncthreads();
    }
#pragma unroll
    for (int j = 0; j < 8; ++j) Ts[rg * 8 + j][col] = acc[j];
#pragma unroll
    for (int i = 0; i < 8; ++i) {
        int e = tid + i * 256;
        int r = e >> 6, c = e & 63;
        Vs[r][c] = Vw[(size_t)h * R_ * DH_ + r * DH_ + c];
    }
    __syncthreads();

    const int colD = tid & 63, rg2 = tid >> 6;  // 4 groups x 16 rows
    float acc2[16];
#pragma unroll
    for (int j = 0; j < 16; ++j) acc2[j] = 0.f;
    for (int k = 0; k < R_; ++k) {
        float vv = Vs[k][colD];
#pragma unroll
        for (int j = 0; j < 16; ++j)
            acc2[j] += Ts[rg2 * 16 + j][k] * vv;
    }
    float bv = bias[h * DH_ + colD];
#pragma unroll
    for (int j = 0; j < 16; ++j) {
        int g = row0 + rg2 * 16 + j;
        int b = g >> 10, m = g & 1023;
        out[(((size_t)b * H_ + h) * M_ + m) * DH_ + colD] = acc2[j] + bv;
    }
}

// ---------------------------------------------------------------------------
// Flash attention f32. Q/K/V layout (B,H,M,DH). Output O in (B,M,DM) layout
// (head-interleaved columns) so the transpose+reshape is free.
// grid: (M/64, H, B), block 256
// ---------------------------------------------------------------------------
__global__ __launch_bounds__(256) void attn_kernel(
    const float* __restrict__ Q, const float* __restrict__ K,
    const float* __restrict__ V, const float* __restrict__ mask,
    float* __restrict__ O)
{
    __shared__ float Qs[64][65];
    __shared__ float KVs[64][65];
    __shared__ float Ps[64][65];
    const int qt = blockIdx.x, h = blockIdx.y, b = blockIdx.z;
    const int tid = threadIdx.x;
    const size_t base = (((size_t)b * H_ + h) * M_) * DH_;

#pragma unroll
    for (int i = 0; i < 16; ++i) {
        int e = tid + i * 256;
        int r = e >> 6, c = e & 63;
        Qs[r][c] = Q[base + (size_t)(qt * 64 + r) * DH_ + c];
    }
    const int i_ = tid >> 2;         // q row 0..63
    const int jc = (tid & 3) * 16;   // 16-col chunk
    float m_i = -INFINITY, l_i = 0.f;
    float o[16];
#pragma unroll
    for (int d = 0; d < 16; ++d) o[d] = 0.f;
    const float scale = 0.125f;  // 1/sqrt(DH)

    for (int kt = 0; kt < 16; ++kt) {
        __syncthreads();
#pragma unroll
        for (int i = 0; i < 16; ++i) {
            int e = tid + i * 256;
            int r = e >> 6, c = e & 63;
            KVs[r][c] = K[base + (size_t)(kt * 64 + r) * DH_ + c];
        }
        __syncthreads();
        float s[16];
#pragma unroll
        for (int j = 0; j < 16; ++j) s[j] = 0.f;
        for (int d = 0; d < 64; ++d) {
            float qv = Qs[i_][d];
#pragma unroll
            for (int j = 0; j < 16; ++j)
                s[j] += qv * KVs[jc + j][d];
        }
        float mx = -INFINITY;
#pragma unroll
        for (int j = 0; j < 16; ++j) {
            s[j] = s[j] * scale + mask[b * M_ + kt * 64 + jc + j];
            mx = fmaxf(mx, s[j]);
        }
        mx = fmaxf(mx, __shfl_xor(mx, 1, 4));
        mx = fmaxf(mx, __shfl_xor(mx, 2, 4));
        float m_new = fmaxf(m_i, mx);
        float corr = expf(m_i - m_new);  // 0 on first tile (m_i=-inf)
        float rs = 0.f;
#pragma unroll
        for (int j = 0; j < 16; ++j) {
            s[j] = expf(s[j] - m_new);
            rs += s[j];
            Ps[i_][jc + j] = s[j];
        }
        rs += __shfl_xor(rs, 1, 4);
        rs += __shfl_xor(rs, 2, 4);
        l_i = l_i * corr + rs;
        m_i = m_new;
#pragma unroll
        for (int d = 0; d < 16; ++d) o[d] *= corr;
        __syncthreads();
#pragma unroll
        for (int i = 0; i < 16; ++i) {
            int e = tid + i * 256;
            int r = e >> 6, c = e & 63;
            KVs[r][c] = V[base + (size_t)(kt * 64 + r) * DH_ + c];
        }
        __syncthreads();
        for (int k = 0; k < 64; ++k) {
            float pv = Ps[i_][k];
#pragma unroll
            for (int d = 0; d < 16; ++d)
                o[d] += pv * KVs[k][jc + d];
        }
    }
    float inv = 1.f / l_i;
    const int gm = qt * 64 + i_;
#pragma unroll
    for (int d = 0; d < 16; ++d)
        O[((size_t)b * M_ + gm) * DM_ + h * DH_ + jc + d] = o[d] * inv;
}

// ---------------------------------------------------------------------------
// Generic tiled f32 GEMM: C(8192 x Nd) = A(8192 x Kd) @ Bw(Kd x Nd)
// 128x128 tile, BK=16, 256 threads, 8x8 microtile. Optional bias + exact GELU.
// grid: (Nd/128, 8192/128)
// ---------------------------------------------------------------------------
template<bool BIAS, bool GELU>
__global__ __launch_bounds__(256) void gemm_f32(
    const float* __restrict__ A, const float* __restrict__ Bw,
    const float* __restrict__ bias, float* __restrict__ C,
    int Kd, int Nd)
{
    __shared__ float As[16][136];  // [k][m]
    __shared__ float Bs[16][136];  // [k][n]
    const int tid = threadIdx.x;
    const int row0 = blockIdx.y * 128, col0 = blockIdx.x * 128;
    const int tx = tid & 15, ty = tid >> 4;

    float acc[8][8];
#pragma unroll
    for (int i = 0; i < 8; ++i)
#pragma unroll
        for (int j = 0; j < 8; ++j) acc[i][j] = 0.f;

    for (int k0 = 0; k0 < Kd; k0 += 16) {
#pragma unroll
        for (int i = 0; i < 8; ++i) {
            int e = tid + i * 256;
            int r = e >> 4, c = e & 15;
            As[c][r] = A[(size_t)(row0 + r) * Kd + k0 + c];
        }
#pragma unroll
        for (int i = 0; i < 8; ++i) {
            int e = tid + i * 256;
            int r = e >> 7, c = e & 127;
            Bs[r][c] = Bw[(size_t)(k0 + r) * Nd + col0 + c];
        }
        __syncthreads();
#pragma unroll
        for (int kk = 0; kk < 16; ++kk) {
            float4 a0 = *reinterpret_cast<const float4*>(&As[kk][ty * 4]);
            float4 a1 = *reinterpret_cast<const float4*>(&As[kk][64 + ty * 4]);
            float4 b0 = *reinterpret_cast<const float4*>(&Bs[kk][tx * 4]);
            float4 b1 = *reinterpret_cast<const float4*>(&Bs[kk][64 + tx * 4]);
            float a[8] = {a0.x, a0.y, a0.z, a0.w, a1.x, a1.y, a1.z, a1.w};
            float bb[8] = {b0.x, b0.y, b0.z, b0.w, b1.x, b1.y, b1.z, b1.w};
#pragma unroll
            for (int i = 0; i < 8; ++i)
#pragma unroll
                for (int j = 0; j < 8; ++j)
                    acc[i][j] += a[i] * bb[j];
        }
        __syncthreads();
    }
#pragma unroll
    for (int ib = 0; ib < 2; ++ib)
#pragma unroll
        for (int i = 0; i < 4; ++i) {
            int row = row0 + ib * 64 + ty * 4 + i;
#pragma unroll
            for (int jb = 0; jb < 2; ++jb)
#pragma unroll
                for (int j = 0; j < 4; ++j) {
                    int colj = col0 + jb * 64 + tx * 4 + j;
                    float v = acc[ib * 4 + i][jb * 4 + j];
                    if (BIAS) v += bias[colj];
                    if (GELU) v = 0.5f * v * (1.f + erff(v * 0.70710678118f));
                    C[(size_t)row * Nd + colj] = v;
                }
        }
}

// ---------------------------------------------------------------------------
// Fused residual + low-rank proj + LayerNorm:
// out[row,:] = LN(res[row,:] + t[row,:] @ W + bias) * g + beta
// t: (NR_,512), W: (512,1024). 8 rows per block, 256 threads.
// ---------------------------------------------------------------------------
__global__ __launch_bounds__(256) void proj_ln_kernel(
    const float* __restrict__ t, const float* __restrict__ W,
    const float* __restrict__ bias, const float* __restrict__ res,
    const float* __restrict__ g, const float* __restrict__ beta,
    float* __restrict__ out)
{
    __shared__ float Ts[8][512];
    __shared__ float red[2][8][4];
    const int row0 = blockIdx.x * 8, tid = threadIdx.x;

#pragma unroll
    for (int i = 0; i < 16; ++i) {
        int e = tid + i * 256;
        int r = e >> 9, c = e & 511;
        Ts[r][c] = t[(size_t)(row0 + r) * 512 + c];
    }
    __syncthreads();

    float acc[8][4];
#pragma unroll
    for (int r = 0; r < 8; ++r)
#pragma unroll
        for (int j = 0; j < 4; ++j) acc[r][j] = 0.f;

    for (int k = 0; k < 512; ++k) {
        float w[4];
#pragma unroll
        for (int j = 0; j < 4; ++j) w[j] = W[(size_t)k * 1024 + tid + j * 256];
#pragma unroll
        for (int r = 0; r < 8; ++r) {
            float tv = Ts[r][k];
#pragma unroll
            for (int j = 0; j < 4; ++j) acc[r][j] += tv * w[j];
        }
    }

    float bsv[4];
#pragma unroll
    for (int j = 0; j < 4; ++j) bsv[j] = bias[tid + j * 256];

#pragma unroll
    for (int r = 0; r < 8; ++r) {
        float sum = 0.f, sq = 0.f;
#pragma unroll
        for (int j = 0; j < 4; ++j) {
            float v = acc[r][j] + res[(size_t)(row0 + r) * 1024 + tid + j * 256] + bsv[j];
            acc[r][j] = v;
            sum += v;
            sq += v * v;
        }
#pragma unroll
        for (int off = 32; off; off >>= 1) {
            sum += __shfl_down(sum, off);
            sq  += __shfl_down(sq, off);
        }
        if ((tid & 63) == 0) { red[0][r][tid >> 6] = sum; red[1][r][tid >> 6] = sq; }
    }
    __syncthreads();

#pragma unroll
    for (int r = 0; r < 8; ++r) {
        float sum = red[0][r][0] + red[0][r][1] + red[0][r][2] + red[0][r][3];
        float sq  = red[1][r][0] + red[1][r][1] + red[1][r][2] + red[1][r][3];
        float mu = sum * (1.f / 1024.f);
        float var = sq * (1.f / 1024.f) - mu * mu;
        float rstd = rsqrtf(var + 1e-12f);
#pragma unroll
        for (int j = 0; j < 4; ++j) {
            int colj = tid + j * 256;
            out[(size_t)(row0 + r) * 1024 + colj] =
                (acc[r][j] - mu) * rstd * g[colj] + beta[colj];
        }
    }
}

// ---------------------------------------------------------------------------
extern "C" void kernel_launch(void* const* d_in, const int* in_sizes, int n_in,
                              void* d_out, int out_size, void* d_ws, size_t ws_size,
                              hipStream_t stream) {
    const float* x    = (const float*)d_in[0];
    const float* mask = (const float*)d_in[1];
    const float* Pq   = (const float*)d_in[2];
    const float* Vq   = (const float*)d_in[3];
    const float* bq   = (const float*)d_in[4];
    const float* Pk   = (const float*)d_in[5];
    const float* Vk   = (const float*)d_in[6];
    const float* bk   = (const float*)d_in[7];
    const float* Pv   = (const float*)d_in[8];
    const float* Vv   = (const float*)d_in[9];
    const float* bv   = (const float*)d_in[10];
    const float* Uo   = (const float*)d_in[11];
    const float* Vo   = (const float*)d_in[12];
    const float* bo   = (const float*)d_in[13];
    const float* g1   = (const float*)d_in[14];
    const float* be1  = (const float*)d_in[15];
    const float* U1   = (const float*)d_in[16];
    const float* V1   = (const float*)d_in[17];
    const float* b1   = (const float*)d_in[18];
    const float* U2   = (const float*)d_in[19];
    const float* V2   = (const float*)d_in[20];
    const float* b2   = (const float*)d_in[21];
    const float* g2   = (const float*)d_in[22];
    const float* be2  = (const float*)d_in[23];
    float* out = (float*)d_out;

    // workspace layout (floats):
    //  [0 .. 33.5M)  Q,K,V,O  (each 8.39M)  -- later reused as hidden (33.5M)
    //  [33.5M .. )   X1 (8.39M)
    //  [41.9M .. )   A  (4.19M)   total 46,137,344 floats = 184.5 MB
    float* w  = (float*)d_ws;
    float* Qb = w;
    float* Kb = w + 8388608;
    float* Vb = w + 16777216;
    float* Ob = w + 25165824;
    float* X1 = w + 33554432;
    float* Ab = w + 41943040;
    float* Hb = w;  // hidden overlaps dead Q/K/V/O

    qkv_kernel<<<dim3(128, 16), 256, 0, stream>>>(x, Pq, Vq, bq, Qb);
    qkv_kernel<<<dim3(128, 16), 256, 0, stream>>>(x, Pk, Vk, bk, Kb);
    qkv_kernel<<<dim3(128, 16), 256, 0, stream>>>(x, Pv, Vv, bv, Vb);

    attn_kernel<<<dim3(16, 16, 8), 256, 0, stream>>>(Qb, Kb, Vb, mask, Ob);

    // t_o = O @ Uo  (8192x512)
    gemm_f32<false, false><<<dim3(4, 64), 256, 0, stream>>>(Ob, Uo, nullptr, Ab, 1024, 512);
    // x1 = LN(x + t_o @ Vo + bo)
    proj_ln_kernel<<<1024, 256, 0, stream>>>(Ab, Vo, bo, x, g1, be1, X1);
    // mid = x1 @ U1  (8192x512)
    gemm_f32<false, false><<<dim3(4, 64), 256, 0, stream>>>(X1, U1, nullptr, Ab, 1024, 512);
    // hidden = gelu(mid @ V1 + b1)  (8192x4096)
    gemm_f32<true, true><<<dim3(32, 64), 256, 0, stream>>>(Ab, V1, b1, Hb, 512, 4096);
    // t2 = hidden @ U2  (8192x512)
    gemm_f32<false, false><<<dim3(4, 64), 256, 0, stream>>>(Hb, U2, nullptr, Ab, 4096, 512);
    // out = LN(x1 + t2 @ V2 + b2)
    proj_ln_kernel<<<1024, 256, 0, stream>>>(Ab, V2, b2, X1, g2, be2, out);
}

// Round 2
// 519.834 us; speedup vs baseline: 8.0481x; 8.0481x over previous
//
#include <hip/hip_runtime.h>
#include <hip/hip_bf16.h>
#include <math.h>

typedef unsigned short u16;
typedef __attribute__((ext_vector_type(8))) short bf16x8;
typedef __attribute__((ext_vector_type(4))) float f32x4;

#define B_ 8
#define M_ 1024
#define DM_ 1024
#define H_ 16
#define DH_ 64
#define NR_ 8192

__device__ __forceinline__ u16 f2bf(float f) {
    unsigned u = __float_as_uint(f);
    u += 0x7FFFu + ((u >> 16) & 1u);
    return (u16)(u >> 16);
}

__device__ __forceinline__ void gload16(const void* g, void* l) {
    __builtin_amdgcn_global_load_lds(
        (const __attribute__((address_space(1))) void*)g,
        (__attribute__((address_space(3))) void*)l, 16, 0, 0);
}

// ---------------------------------------------------------------------------
// x (f32) -> bf16, vectorized
// ---------------------------------------------------------------------------
__global__ __launch_bounds__(256) void conv_bf16(const float* __restrict__ in,
                                                 u16* __restrict__ out) {
    int i = (blockIdx.x * 256 + threadIdx.x) * 4;
    float4 v = *reinterpret_cast<const float4*>(in + i);
    unsigned long long p = (unsigned long long)f2bf(v.x)
                         | ((unsigned long long)f2bf(v.y) << 16)
                         | ((unsigned long long)f2bf(v.z) << 32)
                         | ((unsigned long long)f2bf(v.w) << 48);
    *reinterpret_cast<unsigned long long*>(out + i) = p;
}

// ---------------------------------------------------------------------------
// Wt[h*64+e][k] = sum_r P[h][k][r] * V[h][r][e]   (bf16 out, (N=1024,K=1024))
// grid (16, 8) : h, k-chunk of 128
// ---------------------------------------------------------------------------
__global__ __launch_bounds__(256) void build_w(const float* __restrict__ P,
                                               const float* __restrict__ Vw,
                                               u16* __restrict__ Wt) {
    __shared__ float Ps[128][33];
    __shared__ float Vs[32][65];
    const int h = blockIdx.x, kc = blockIdx.y * 128, tid = threadIdx.x;
#pragma unroll
    for (int i = 0; i < 16; ++i) {
        int e = tid + i * 256;
        int r = e >> 5, c = e & 31;
        Ps[r][c] = P[(size_t)h * 32768 + (size_t)(kc + r) * 32 + c];
    }
#pragma unroll
    for (int i = 0; i < 8; ++i) {
        int e = tid + i * 256;
        int r = e >> 6, c = e & 63;
        Vs[r][c] = Vw[(size_t)h * 2048 + r * 64 + c];
    }
    __syncthreads();
    const int e0 = tid & 63, kg = tid >> 6;
#pragma unroll
    for (int kk = 0; kk < 32; ++kk) {
        int kl = kg * 32 + kk;
        float acc = 0.f;
#pragma unroll
        for (int r = 0; r < 32; ++r) acc += Ps[kl][r] * Vs[r][e0];
        Wt[(size_t)(h * 64 + e0) * 1024 + kc + kl] = f2bf(acc);
    }
}

// ---------------------------------------------------------------------------
// transpose f32 (R x C) -> bf16 (C x R).  grid (C/64, R/64)
// ---------------------------------------------------------------------------
__global__ __launch_bounds__(256) void transpose_w(const float* __restrict__ in,
                                                   u16* __restrict__ out,
                                                   int R, int C) {
    __shared__ float t[64][65];
    const int rb = blockIdx.y * 64, cb = blockIdx.x * 64, tid = threadIdx.x;
#pragma unroll
    for (int i = 0; i < 16; ++i) {
        int e = tid + i * 256;
        int r = e >> 6, c = e & 63;
        t[r][c] = in[(size_t)(rb + r) * C + cb + c];
    }
    __syncthreads();
#pragma unroll
    for (int i = 0; i < 16; ++i) {
        int e = tid + i * 256;
        int r = e >> 6, c = e & 63;
        out[(size_t)(cb + r) * R + rb + c] = f2bf(t[c][r]);
    }
}

// ---------------------------------------------------------------------------
// bf16 MFMA GEMM: C(8192 x N) = A(8192 x K) @ Bt(N x K)^T
// 128x128 tile, BK=64, 4 waves (2x2 of 64x64), global_load_lds staging with
// st-16x32 XOR swizzle (T2).  EPI: 0 bf16, 1 qkv-scatter+bias, 2 bias+gelu
// bf16, 3 f32.
// ---------------------------------------------------------------------------
template <int EPI>
__global__ __launch_bounds__(256) void gemm_bf16(const u16* __restrict__ A,
                                                 const u16* __restrict__ Bt,
                                                 const float* __restrict__ bias,
                                                 void* __restrict__ Cout,
                                                 int K, int N) {
    __shared__ u16 As[128 * 64];
    __shared__ u16 Bs[128 * 64];
    const int tid = threadIdx.x;
    const int lane = tid & 63, wv = tid >> 6;
    const int row0 = blockIdx.y * 128, col0 = blockIdx.x * 128;
    const int frow = lane & 15, fk8 = lane >> 4;
    const int wm = (wv >> 1) * 64, wn = (wv & 1) * 64;

    f32x4 acc[4][4];
    const f32x4 z4 = {0.f, 0.f, 0.f, 0.f};
#pragma unroll
    for (int i = 0; i < 4; ++i)
#pragma unroll
        for (int j = 0; j < 4; ++j) acc[i][j] = z4;

    for (int k0 = 0; k0 < K; k0 += 64) {
#pragma unroll
        for (int i = 0; i < 4; ++i) {
            int rr = (i * 4 + wv) * 8 + (lane >> 3);
            int cc = ((lane & 7) ^ (rr & 7)) * 8;
            gload16(A + (size_t)(row0 + rr) * K + k0 + cc,
                    (char*)As + (i * 4 + wv) * 1024);
            gload16(Bt + (size_t)(col0 + rr) * K + k0 + cc,
                    (char*)Bs + (i * 4 + wv) * 1024);
        }
        asm volatile("s_waitcnt vmcnt(0)" ::: "memory");
        __syncthreads();
#pragma unroll
        for (int kf = 0; kf < 2; ++kf) {
            bf16x8 af[4], bfr[4];
#pragma unroll
            for (int mf = 0; mf < 4; ++mf) {
                int r = wm + mf * 16 + frow;
                int c16 = (kf * 4 + fk8) ^ (r & 7);
                af[mf] = *reinterpret_cast<const bf16x8*>((char*)As + r * 128 + c16 * 16);
            }
#pragma unroll
            for (int nf = 0; nf < 4; ++nf) {
                int r = wn + nf * 16 + frow;
                int c16 = (kf * 4 + fk8) ^ (r & 7);
                bfr[nf] = *reinterpret_cast<const bf16x8*>((char*)Bs + r * 128 + c16 * 16);
            }
#pragma unroll
            for (int mf = 0; mf < 4; ++mf)
#pragma unroll
                for (int nf = 0; nf < 4; ++nf)
                    acc[mf][nf] = __builtin_amdgcn_mfma_f32_16x16x32_bf16(
                        af[mf], bfr[nf], acc[mf][nf], 0, 0, 0);
        }
        __syncthreads();
    }

    const int orow = fk8 * 4, ocol = frow;
#pragma unroll
    for (int mf = 0; mf < 4; ++mf)
#pragma unroll
        for (int nf = 0; nf < 4; ++nf)
#pragma unroll
            for (int j = 0; j < 4; ++j) {
                int row = row0 + wm + mf * 16 + orow + j;
                int col = col0 + wn + nf * 16 + ocol;
                float v = acc[mf][nf][j];
                if (EPI == 1) {
                    v += bias[col];
                    int b = row >> 10, m = row & 1023, h = col >> 6, e = col & 63;
                    ((u16*)Cout)[(((size_t)(b * 16 + h) << 10) + m) * 64 + e] = f2bf(v);
                } else if (EPI == 2) {
                    v += bias[col];
                    v = 0.5f * v * (1.f + erff(v * 0.70710678118f));
                    ((u16*)Cout)[(size_t)row * N + col] = f2bf(v);
                } else if (EPI == 3) {
                    ((float*)Cout)[(size_t)row * N + col] = v;
                } else {
                    ((u16*)Cout)[(size_t)row * N + col] = f2bf(v);
                }
            }
}

// ---------------------------------------------------------------------------
// MFMA flash attention.  Q,K,V bf16 (B*H, M, 64).  O bf16 (B*M, 1024)
// head-interleaved.  grid (M/64, H, B), 256 thr = 4 waves, 16 q-rows/wave.
// ---------------------------------------------------------------------------
__global__ __launch_bounds__(256) void attn_mfma(const u16* __restrict__ Q,
                                                 const u16* __restrict__ K,
                                                 const u16* __restrict__ V,
                                                 const float* __restrict__ mask,
                                                 u16* __restrict__ O) {
    __shared__ u16 Qs[64 * 64];
    __shared__ u16 Ks[64 * 64];
    __shared__ u16 Vt[64 * 64];   // [d][key], swizzled
    __shared__ u16 Pl[4 * 16 * 72];
    const int qt = blockIdx.x, h = blockIdx.y, b = blockIdx.z;
    const int tid = threadIdx.x, lane = tid & 63, wv = tid >> 6;
    const int frow = lane & 15, fk8 = lane >> 4;
    const size_t base = (size_t)(b * 16 + h) * 1024 * 64;

#pragma unroll
    for (int i = 0; i < 2; ++i) {
        int rr = (i * 4 + wv) * 8 + (lane >> 3);
        int cc = ((lane & 7) ^ (rr & 7)) * 8;
        gload16(Q + base + (size_t)(qt * 64 + rr) * 64 + cc,
                (char*)Qs + (i * 4 + wv) * 1024);
    }

    float m_i[4], l_i[4];
    const f32x4 z4 = {0.f, 0.f, 0.f, 0.f};
    f32x4 o_acc[4];
#pragma unroll
    for (int j = 0; j < 4; ++j) { m_i[j] = -INFINITY; l_i[j] = 0.f; o_acc[j] = z4; }

    const int vkey = tid & 63, vd0 = (tid >> 6) * 16;

    for (int kt = 0; kt < 16; ++kt) {
        __syncthreads();
#pragma unroll
        for (int i = 0; i < 2; ++i) {
            int rr = (i * 4 + wv) * 8 + (lane >> 3);
            int cc = ((lane & 7) ^ (rr & 7)) * 8;
            gload16(K + base + (size_t)(kt * 64 + rr) * 64 + cc,
                    (char*)Ks + (i * 4 + wv) * 1024);
        }
        {
            const u16* vsrc = V + base + (size_t)(kt * 64 + vkey) * 64 + vd0;
            uint4 va = *reinterpret_cast<const uint4*>(vsrc);
            uint4 vb = *reinterpret_cast<const uint4*>(vsrc + 8);
            u16 vv[16];
            *reinterpret_cast<uint4*>(vv) = va;
            *reinterpret_cast<uint4*>(vv + 8) = vb;
#pragma unroll
            for (int i = 0; i < 16; ++i) {
                int d = vd0 + i;
                int slot = (vkey >> 3) ^ (d & 7);
                Vt[d * 64 + slot * 8 + (vkey & 7)] = vv[i];
            }
        }
        asm volatile("s_waitcnt vmcnt(0)" ::: "memory");
        __syncthreads();

        // S = Q K^T  (wave's 16 rows x 64 keys)
        f32x4 sacc[4];
#pragma unroll
        for (int nf = 0; nf < 4; ++nf) sacc[nf] = z4;
#pragma unroll
        for (int kf = 0; kf < 2; ++kf) {
            int qr = wv * 16 + frow;
            int qc16 = (kf * 4 + fk8) ^ (qr & 7);
            bf16x8 aq = *reinterpret_cast<const bf16x8*>((char*)Qs + qr * 128 + qc16 * 16);
#pragma unroll
            for (int nf = 0; nf < 4; ++nf) {
                int kr = nf * 16 + frow;
                int kc16 = (kf * 4 + fk8) ^ (kr & 7);
                bf16x8 bk = *reinterpret_cast<const bf16x8*>((char*)Ks + kr * 128 + kc16 * 16);
                sacc[nf] = __builtin_amdgcn_mfma_f32_16x16x32_bf16(aq, bk, sacc[nf], 0, 0, 0);
            }
        }

        // online softmax: lane holds S[qrow=fk8*4+j][key=nf*16+frow]
        float sval[4][4], mx[4];
#pragma unroll
        for (int j = 0; j < 4; ++j) mx[j] = -INFINITY;
#pragma unroll
        for (int nf = 0; nf < 4; ++nf) {
            float mval = mask[b * M_ + kt * 64 + nf * 16 + frow];
#pragma unroll
            for (int j = 0; j < 4; ++j) {
                float v = sacc[nf][j] * 0.125f + mval;
                sval[nf][j] = v;
                mx[j] = fmaxf(mx[j], v);
            }
        }
#pragma unroll
        for (int j = 0; j < 4; ++j) {
            float m = mx[j];
            m = fmaxf(m, __shfl_xor(m, 1));
            m = fmaxf(m, __shfl_xor(m, 2));
            m = fmaxf(m, __shfl_xor(m, 4));
            m = fmaxf(m, __shfl_xor(m, 8));
            float mnew = fmaxf(m_i[j], m);
            float c = (m_i[j] == -INFINITY) ? 0.f : __expf(m_i[j] - mnew);
            float rs = 0.f;
#pragma unroll
            for (int nf = 0; nf < 4; ++nf) {
                float p = __expf(sval[nf][j] - mnew);
                rs += p;
                Pl[wv * 1152 + (fk8 * 4 + j) * 72 + nf * 16 + frow] = f2bf(p);
            }
            rs += __shfl_xor(rs, 1);
            rs += __shfl_xor(rs, 2);
            rs += __shfl_xor(rs, 4);
            rs += __shfl_xor(rs, 8);
            l_i[j] = l_i[j] * c + rs;
            m_i[j] = mnew;
#pragma unroll
            for (int nf = 0; nf < 4; ++nf) o_acc[nf][j] *= c;
        }

        // O += P @ V
#pragma unroll
        for (int kf = 0; kf < 2; ++kf) {
            bf16x8 ap = *reinterpret_cast<const bf16x8*>(
                &Pl[wv * 1152 + frow * 72 + fk8 * 8 + kf * 32]);
#pragma unroll
            for (int nf = 0; nf < 4; ++nf) {
                int vr = nf * 16 + frow;
                int vc16 = (kf * 4 + fk8) ^ (vr & 7);
                bf16x8 bv = *reinterpret_cast<const bf16x8*>((char*)Vt + vr * 128 + vc16 * 16);
                o_acc[nf] = __builtin_amdgcn_mfma_f32_16x16x32_bf16(ap, bv, o_acc[nf], 0, 0, 0);
            }
        }
    }

#pragma unroll
    for (int j = 0; j < 4; ++j) {
        float inv = 1.f / l_i[j];
        int grow = qt * 64 + wv * 16 + fk8 * 4 + j;
        size_t obase = ((size_t)(b * M_ + grow)) * DM_ + h * 64;
#pragma unroll
        for (int nf = 0; nf < 4; ++nf)
            O[obase + nf * 16 + frow] = f2bf(o_acc[nf][j] * inv);
    }
}

// ---------------------------------------------------------------------------
// LN: out = LN(y + res + bias) * g + beta ; optional bf16 copy.  1 row/block.
// ---------------------------------------------------------------------------
template <bool WBF>
__global__ __launch_bounds__(256) void ln_kernel(const float* __restrict__ y,
                                                 const float* __restrict__ res,
                                                 const float* __restrict__ bias,
                                                 const float* __restrict__ g,
                                                 const float* __restrict__ beta,
                                                 float* __restrict__ outf,
                                                 u16* __restrict__ outb) {
    __shared__ float red[2][4];
    const int row = blockIdx.x, tid = threadIdx.x;
    const size_t base = (size_t)row * 1024 + tid * 4;
    float4 v = *reinterpret_cast<const float4*>(y + base);
    float4 r = *reinterpret_cast<const float4*>(res + base);
    float4 bb = *reinterpret_cast<const float4*>(bias + tid * 4);
    v.x += r.x + bb.x; v.y += r.y + bb.y; v.z += r.z + bb.z; v.w += r.w + bb.w;
    float sum = v.x + v.y + v.z + v.w;
    float sq = v.x * v.x + v.y * v.y + v.z * v.z + v.w * v.w;
#pragma unroll
    for (int off = 32; off; off >>= 1) {
        sum += __shfl_down(sum, off);
        sq += __shfl_down(sq, off);
    }
    if ((tid & 63) == 0) { red[0][tid >> 6] = sum; red[1][tid >> 6] = sq; }
    __syncthreads();
    sum = red[0][0] + red[0][1] + red[0][2] + red[0][3];
    sq = red[1][0] + red[1][1] + red[1][2] + red[1][3];
    float mu = sum * (1.f / 1024.f);
    float var = sq * (1.f / 1024.f) - mu * mu;
    float rstd = rsqrtf(var + 1e-12f);
    float4 gg = *reinterpret_cast<const float4*>(g + tid * 4);
    float4 be = *reinterpret_cast<const float4*>(beta + tid * 4);
    float4 o;
    o.x = (v.x - mu) * rstd * gg.x + be.x;
    o.y = (v.y - mu) * rstd * gg.y + be.y;
    o.z = (v.z - mu) * rstd * gg.z + be.z;
    o.w = (v.w - mu) * rstd * gg.w + be.w;
    *reinterpret_cast<float4*>(outf + base) = o;
    if (WBF) {
        unsigned long long p = (unsigned long long)f2bf(o.x)
                             | ((unsigned long long)f2bf(o.y) << 16)
                             | ((unsigned long long)f2bf(o.z) << 32)
                             | ((unsigned long long)f2bf(o.w) << 48);
        *reinterpret_cast<unsigned long long*>(outb + base) = p;
    }
}

// ---------------------------------------------------------------------------
extern "C" void kernel_launch(void* const* d_in, const int* in_sizes, int n_in,
                              void* d_out, int out_size, void* d_ws, size_t ws_size,
                              hipStream_t stream) {
    const float* x    = (const float*)d_in[0];
    const float* mask = (const float*)d_in[1];
    const float* Pq   = (const float*)d_in[2];
    const float* Vq   = (const float*)d_in[3];
    const float* bq   = (const float*)d_in[4];
    const float* Pk   = (const float*)d_in[5];
    const float* Vk   = (const float*)d_in[6];
    const float* bk   = (const float*)d_in[7];
    const float* Pv   = (const float*)d_in[8];
    const float* Vv   = (const float*)d_in[9];
    const float* bv   = (const float*)d_in[10];
    const float* Uo   = (const float*)d_in[11];
    const float* Vo   = (const float*)d_in[12];
    const float* bo   = (const float*)d_in[13];
    const float* g1   = (const float*)d_in[14];
    const float* be1  = (const float*)d_in[15];
    const float* U1   = (const float*)d_in[16];
    const float* V1   = (const float*)d_in[17];
    const float* b1   = (const float*)d_in[18];
    const float* U2   = (const float*)d_in[19];
    const float* V2   = (const float*)d_in[20];
    const float* b2   = (const float*)d_in[21];
    const float* g2   = (const float*)d_in[22];
    const float* be2  = (const float*)d_in[23];
    float* out = (float*)d_out;

    char* ws = (char*)d_ws;
    u16* Wqt = (u16*)(ws + 0);            // 2 MB
    u16* Wkt = (u16*)(ws + 2097152);      // 2 MB
    u16* Wvt = (u16*)(ws + 4194304);      // 2 MB
    u16* Uot = (u16*)(ws + 6291456);      // 1 MB (512 x 1024)
    u16* Vot = (u16*)(ws + 7340032);      // 1 MB (1024 x 512)
    u16* U1t = (u16*)(ws + 8388608);      // 1 MB (512 x 1024)
    u16* V1t = (u16*)(ws + 9437184);      // 4 MB (4096 x 512)
    u16* U2t = (u16*)(ws + 13631488);     // 4 MB (512 x 4096)
    u16* V2t = (u16*)(ws + 17825792);     // 1 MB (1024 x 512)
    u16* Xb  = (u16*)(ws + 18874368);     // 16 MB (x bf16; reused as x1 bf16)
    u16* Qb  = (u16*)(ws + 35651584);     // 16 MB
    u16* Kb  = (u16*)(ws + 52428800);     // 16 MB
    u16* Vb  = (u16*)(ws + 69206016);     // 16 MB
    u16* Ob  = (u16*)(ws + 85983232);     // 16 MB
    u16* Hb  = (u16*)(ws + 35651584);     // 64 MB, overlaps dead Q/K/V/O
    u16* Tb  = (u16*)(ws + 102760448);    // 8 MB (8192 x 512 bf16)
    float* Yf  = (float*)(ws + 111149056); // 32 MB
    float* X1f = (float*)(ws + 144703488); // 32 MB ; end = 178,257,920

    // --- precompute (bf16 weights) ---
    conv_bf16<<<8192, 256, 0, stream>>>(x, Xb);
    build_w<<<dim3(16, 8), 256, 0, stream>>>(Pq, Vq, Wqt);
    build_w<<<dim3(16, 8), 256, 0, stream>>>(Pk, Vk, Wkt);
    build_w<<<dim3(16, 8), 256, 0, stream>>>(Pv, Vv, Wvt);
    transpose_w<<<dim3(8, 16), 256, 0, stream>>>(Uo, Uot, 1024, 512);
    transpose_w<<<dim3(16, 8), 256, 0, stream>>>(Vo, Vot, 512, 1024);
    transpose_w<<<dim3(8, 16), 256, 0, stream>>>(U1, U1t, 1024, 512);
    transpose_w<<<dim3(64, 8), 256, 0, stream>>>(V1, V1t, 512, 4096);
    transpose_w<<<dim3(8, 64), 256, 0, stream>>>(U2, U2t, 4096, 512);
    transpose_w<<<dim3(16, 8), 256, 0, stream>>>(V2, V2t, 512, 1024);

    // --- QKV ---
    gemm_bf16<1><<<dim3(8, 64), 256, 0, stream>>>(Xb, Wqt, bq, Qb, 1024, 1024);
    gemm_bf16<1><<<dim3(8, 64), 256, 0, stream>>>(Xb, Wkt, bk, Kb, 1024, 1024);
    gemm_bf16<1><<<dim3(8, 64), 256, 0, stream>>>(Xb, Wvt, bv, Vb, 1024, 1024);

    // --- attention ---
    attn_mfma<<<dim3(16, 16, 8), 256, 0, stream>>>(Qb, Kb, Vb, mask, Ob);

    // --- attn out proj + LN1 ---
    gemm_bf16<0><<<dim3(4, 64), 256, 0, stream>>>(Ob, Uot, nullptr, Tb, 1024, 512);
    gemm_bf16<3><<<dim3(8, 64), 256, 0, stream>>>(Tb, Vot, nullptr, Yf, 512, 1024);
    ln_kernel<true><<<8192, 256, 0, stream>>>(Yf, x, bo, g1, be1, X1f, Xb);

    // --- FFN + LN2 ---
    gemm_bf16<0><<<dim3(4, 64), 256, 0, stream>>>(Xb, U1t, nullptr, Tb, 1024, 512);
    gemm_bf16<2><<<dim3(32, 64), 256, 0, stream>>>(Tb, V1t, b1, Hb, 512, 4096);
    gemm_bf16<0><<<dim3(4, 64), 256, 0, stream>>>(Hb, U2t, nullptr, Tb, 4096, 512);
    gemm_bf16<3><<<dim3(8, 64), 256, 0, stream>>>(Tb, V2t, nullptr, Yf, 512, 1024);
    ln_kernel<false><<<8192, 256, 0, stream>>>(Yf, X1f, b2, g2, be2, out, nullptr);
}

// Round 3
// 417.434 us; speedup vs baseline: 10.0223x; 1.2453x over previous
//
#include <hip/hip_runtime.h>
#include <hip/hip_bf16.h>
#include <math.h>

typedef unsigned short u16;
typedef unsigned int u32;
typedef __attribute__((ext_vector_type(8))) short bf16x8;
typedef __attribute__((ext_vector_type(4))) float f32x4;

#define B_ 8
#define M_ 1024
#define DM_ 1024
#define H_ 16
#define DH_ 64
#define NR_ 8192

__device__ __forceinline__ u16 f2bf(float f) {
    unsigned u = __float_as_uint(f);
    u += 0x7FFFu + ((u >> 16) & 1u);
    return (u16)(u >> 16);
}

__device__ __forceinline__ void gload16(const void* g, void* l) {
    __builtin_amdgcn_global_load_lds(
        (const __attribute__((address_space(1))) void*)g,
        (__attribute__((address_space(3))) void*)l, 16, 0, 0);
}

// ---------------------------------------------------------------------------
// x (f32) -> bf16, vectorized
// ---------------------------------------------------------------------------
__global__ __launch_bounds__(256) void conv_bf16(const float* __restrict__ in,
                                                 u16* __restrict__ out) {
    int i = (blockIdx.x * 256 + threadIdx.x) * 4;
    float4 v = *reinterpret_cast<const float4*>(in + i);
    unsigned long long p = (unsigned long long)f2bf(v.x)
                         | ((unsigned long long)f2bf(v.y) << 16)
                         | ((unsigned long long)f2bf(v.z) << 32)
                         | ((unsigned long long)f2bf(v.w) << 48);
    *reinterpret_cast<unsigned long long*>(out + i) = p;
}

// ---------------------------------------------------------------------------
// Pt[(h*32+r)][k] = P[h][k][r]  bf16, (1536 x 1024) for concat q|k|v handled
// by calling 3x with different out offsets.  grid (16, 8): h, k-chunk 128.
// ---------------------------------------------------------------------------
__global__ __launch_bounds__(256) void prep_p(const float* __restrict__ P,
                                              u16* __restrict__ Pt) {
    __shared__ float Ps[128][33];
    const int h = blockIdx.x, kc = blockIdx.y * 128, tid = threadIdx.x;
#pragma unroll
    for (int i = 0; i < 16; ++i) {
        int e = tid + i * 256;
        int kk = e >> 5, r = e & 31;
        Ps[kk][r] = P[(size_t)h * 32768 + (size_t)(kc + kk) * 32 + r];
    }
    __syncthreads();
#pragma unroll
    for (int i = 0; i < 16; ++i) {
        int e = tid + i * 256;
        int r = e >> 7, k = e & 127;
        Pt[(size_t)(h * 32 + r) * 1024 + kc + k] = f2bf(Ps[k][r]);
    }
}

// ---------------------------------------------------------------------------
// Ft[h][e][r] = V[h][r][e]  bf16, row stride 40 (16B-aligned).  grid (16).
// ---------------------------------------------------------------------------
__global__ __launch_bounds__(256) void prep_f(const float* __restrict__ V,
                                              u16* __restrict__ Ft) {
    __shared__ float Vs[32][65];
    const int h = blockIdx.x, tid = threadIdx.x;
#pragma unroll
    for (int i = 0; i < 8; ++i) {
        int e = tid + i * 256;
        int r = e >> 6, c = e & 63;
        Vs[r][c] = V[(size_t)h * 2048 + r * 64 + c];
    }
    __syncthreads();
#pragma unroll
    for (int i = 0; i < 8; ++i) {
        int idx = tid + i * 256;
        int e = idx >> 5, r = idx & 31;
        Ft[(size_t)h * 2560 + e * 40 + r] = f2bf(Vs[r][e]);
    }
}

// ---------------------------------------------------------------------------
// transpose f32 (R x C) -> bf16 (C x R).  grid (C/64, R/64)
// ---------------------------------------------------------------------------
__global__ __launch_bounds__(256) void transpose_w(const float* __restrict__ in,
                                                   u16* __restrict__ out,
                                                   int R, int C) {
    __shared__ float t[64][65];
    const int rb = blockIdx.y * 64, cb = blockIdx.x * 64, tid = threadIdx.x;
#pragma unroll
    for (int i = 0; i < 16; ++i) {
        int e = tid + i * 256;
        int r = e >> 6, c = e & 63;
        t[r][c] = in[(size_t)(rb + r) * C + cb + c];
    }
    __syncthreads();
#pragma unroll
    for (int i = 0; i < 16; ++i) {
        int e = tid + i * 256;
        int r = e >> 6, c = e & 63;
        out[(size_t)(cb + r) * R + rb + c] = f2bf(t[c][r]);
    }
}

// ---------------------------------------------------------------------------
// bf16 MFMA GEMM: C(8192 x N) = A(8192 x K) @ Bt(N x K)^T
// BM=128, BN=NF*32, BK=64, 4 waves (2x2), global_load_lds + XOR swizzle.
// XCD-chunked block remap (grid must be divisible by 8).
// EPI: 0 bf16, 2 bias+gelu bf16, 3 f32.
// ---------------------------------------------------------------------------
template <int EPI, int NF>
__global__ __launch_bounds__(256) void gemm_bf16(const u16* __restrict__ A,
                                                 const u16* __restrict__ Bt,
                                                 const float* __restrict__ bias,
                                                 void* __restrict__ Cout,
                                                 int K, int N) {
    constexpr int BN = NF * 32;
    __shared__ u16 As[128 * 64];
    __shared__ u16 Bs[BN * 64];
    const int tid = threadIdx.x;
    const int lane = tid & 63, wv = tid >> 6;

    // XCD-chunked swizzle: consecutive dispatch ids land on different XCDs;
    // remap so each XCD owns a contiguous row-band (A-panel L2 reuse).
    const int NX = gridDim.x;
    const int flat = blockIdx.x + blockIdx.y * NX;
    const int q = (NX * gridDim.y) >> 3;
    const int nid = (flat & 7) * q + (flat >> 3);
    const int row0 = (nid / NX) * 128, col0 = (nid % NX) * BN;

    const int frow = lane & 15, fk8 = lane >> 4;
    const int wm = (wv >> 1) * 64, wn = (wv & 1) * (BN / 2);

    f32x4 acc[4][NF];
    const f32x4 z4 = {0.f, 0.f, 0.f, 0.f};
#pragma unroll
    for (int i = 0; i < 4; ++i)
#pragma unroll
        for (int j = 0; j < NF; ++j) acc[i][j] = z4;

    for (int k0 = 0; k0 < K; k0 += 64) {
#pragma unroll
        for (int i = 0; i < 4; ++i) {
            int rr = (i * 4 + wv) * 8 + (lane >> 3);
            int cc = ((lane & 7) ^ (rr & 7)) * 8;
            gload16(A + (size_t)(row0 + rr) * K + k0 + cc,
                    (char*)As + (i * 4 + wv) * 1024);
        }
#pragma unroll
        for (int i = 0; i < NF; ++i) {
            int rr = (i * 4 + wv) * 8 + (lane >> 3);
            int cc = ((lane & 7) ^ (rr & 7)) * 8;
            gload16(Bt + (size_t)(col0 + rr) * K + k0 + cc,
                    (char*)Bs + (i * 4 + wv) * 1024);
        }
        asm volatile("s_waitcnt vmcnt(0)" ::: "memory");
        __syncthreads();
#pragma unroll
        for (int kf = 0; kf < 2; ++kf) {
            bf16x8 af[4], bfr[NF];
#pragma unroll
            for (int mf = 0; mf < 4; ++mf) {
                int r = wm + mf * 16 + frow;
                int c16 = (kf * 4 + fk8) ^ (r & 7);
                af[mf] = *reinterpret_cast<const bf16x8*>((char*)As + r * 128 + c16 * 16);
            }
#pragma unroll
            for (int nf = 0; nf < NF; ++nf) {
                int r = wn + nf * 16 + frow;
                int c16 = (kf * 4 + fk8) ^ (r & 7);
                bfr[nf] = *reinterpret_cast<const bf16x8*>((char*)Bs + r * 128 + c16 * 16);
            }
#pragma unroll
            for (int mf = 0; mf < 4; ++mf)
#pragma unroll
                for (int nf = 0; nf < NF; ++nf)
                    acc[mf][nf] = __builtin_amdgcn_mfma_f32_16x16x32_bf16(
                        af[mf], bfr[nf], acc[mf][nf], 0, 0, 0);
        }
        __syncthreads();
    }

    const int orow = fk8 * 4, ocol = frow;
#pragma unroll
    for (int mf = 0; mf < 4; ++mf)
#pragma unroll
        for (int nf = 0; nf < NF; ++nf)
#pragma unroll
            for (int j = 0; j < 4; ++j) {
                int row = row0 + wm + mf * 16 + orow + j;
                int col = col0 + wn + nf * 16 + ocol;
                float v = acc[mf][nf][j];
                if (EPI == 2) {
                    v += bias[col];
                    v = 0.5f * v * (1.f + erff(v * 0.70710678118f));
                    ((u16*)Cout)[(size_t)row * N + col] = f2bf(v);
                } else if (EPI == 3) {
                    ((float*)Cout)[(size_t)row * N + col] = v;
                } else {
                    ((u16*)Cout)[(size_t)row * N + col] = f2bf(v);
                }
            }
}

// ---------------------------------------------------------------------------
// QKV stage 2: per head, [Q|K|V](m, e) = Tmp(m, h*32+r | +512 | +1024) @
// Ft(e, r)^T + bias.  K=32 -> one MFMA per (factor, nf).  grid (128, 16).
// ---------------------------------------------------------------------------
__global__ __launch_bounds__(256) void qkv_s2(const u16* __restrict__ Tmp,
                                              const u16* __restrict__ Ftq,
                                              const u16* __restrict__ Ftk,
                                              const u16* __restrict__ Ftv,
                                              const float* __restrict__ bq,
                                              const float* __restrict__ bk,
                                              const float* __restrict__ bv,
                                              u16* __restrict__ Q,
                                              u16* __restrict__ K,
                                              u16* __restrict__ V) {
    __shared__ u16 Ts[64 * 104];   // [row][sect*32 + r], stride 104 (2-way free)
    const int m0 = blockIdx.x * 64, h = blockIdx.y, tid = threadIdx.x;
    const int lane = tid & 63, wv = tid >> 6;
    const int frow = lane & 15, fk8 = lane >> 4;

    // stage Tmp slices (q,k,v ranks for head h)
    {
        const int row = tid >> 2, seg = tid & 3;
#pragma unroll
        for (int sect = 0; sect < 3; ++sect) {
            int off = sect * 512 + h * 32;
            uint4 v = *reinterpret_cast<const uint4*>(
                Tmp + (size_t)(m0 + row) * 1536 + off + seg * 8);
            *reinterpret_cast<uint4*>(&Ts[row * 104 + sect * 32 + seg * 8]) = v;
        }
    }
    __syncthreads();

    const u16* Fts[3] = {Ftq, Ftk, Ftv};
    const float* bs[3] = {bq, bk, bv};
    u16* outs[3] = {Q, K, V};

    f32x4 acc[3][4];
    const f32x4 z4 = {0.f, 0.f, 0.f, 0.f};
#pragma unroll
    for (int f = 0; f < 3; ++f) {
        bf16x8 a = *reinterpret_cast<const bf16x8*>(
            &Ts[(wv * 16 + frow) * 104 + f * 32 + fk8 * 8]);
#pragma unroll
        for (int nf = 0; nf < 4; ++nf) {
            int e = nf * 16 + frow;
            bf16x8 b = *reinterpret_cast<const bf16x8*>(
                Fts[f] + (size_t)h * 2560 + e * 40 + fk8 * 8);
            acc[f][nf] = __builtin_amdgcn_mfma_f32_16x16x32_bf16(a, b, z4, 0, 0, 0);
        }
    }

    const int bb = m0 >> 10;
#pragma unroll
    for (int f = 0; f < 3; ++f)
#pragma unroll
        for (int nf = 0; nf < 4; ++nf) {
            int e = nf * 16 + frow;
            float bias = bs[f][h * 64 + e];
#pragma unroll
            for (int j = 0; j < 4; ++j) {
                int m = m0 + wv * 16 + fk8 * 4 + j;
                outs[f][(((size_t)(bb * 16 + h) << 10) + (m & 1023)) * 64 + e] =
                    f2bf(acc[f][nf][j] + bias);
            }
        }
}

// ---------------------------------------------------------------------------
// MFMA flash attention.  Q,K,V bf16 (B*H, M, 64).  O bf16 (B*M, 1024).
// 1D grid 2048 with XCD remap: each XCD owns 16 (b,h) pairs, qt innermost
// -> K/V stay L2-resident.  4 waves, 16 q-rows/wave, KVBLK=64.
// ---------------------------------------------------------------------------
__global__ __launch_bounds__(256) void attn_mfma(const u16* __restrict__ Q,
                                                 const u16* __restrict__ K,
                                                 const u16* __restrict__ V,
                                                 const float* __restrict__ mask,
                                                 u16* __restrict__ O) {
    __shared__ u16 Qs[64 * 64];
    __shared__ u16 Ks[64 * 64];
    __shared__ u16 Vt[64 * 64];   // [d][key], swizzled
    __shared__ u16 Pl[4 * 16 * 72];
    const int flat = blockIdx.x;
    const int nid = (flat & 7) * 256 + (flat >> 3);
    const int hb = nid >> 4, qt = nid & 15;
    const int b = hb >> 4, h = hb & 15;
    const int tid = threadIdx.x, lane = tid & 63, wv = tid >> 6;
    const int frow = lane & 15, fk8 = lane >> 4;
    const size_t base = (size_t)hb * 1024 * 64;

#pragma unroll
    for (int i = 0; i < 2; ++i) {
        int rr = (i * 4 + wv) * 8 + (lane >> 3);
        int cc = ((lane & 7) ^ (rr & 7)) * 8;
        gload16(Q + base + (size_t)(qt * 64 + rr) * 64 + cc,
                (char*)Qs + (i * 4 + wv) * 1024);
    }

    float m_i[4], l_i[4];
    const f32x4 z4 = {0.f, 0.f, 0.f, 0.f};
    f32x4 o_acc[4];
#pragma unroll
    for (int j = 0; j < 4; ++j) { m_i[j] = -1e30f; l_i[j] = 0.f; o_acc[j] = z4; }

    const int vkey = (tid & 31) * 2, vd0 = (tid >> 5) * 8;

    for (int kt = 0; kt < 16; ++kt) {
        __syncthreads();
#pragma unroll
        for (int i = 0; i < 2; ++i) {
            int rr = (i * 4 + wv) * 8 + (lane >> 3);
            int cc = ((lane & 7) ^ (rr & 7)) * 8;
            gload16(K + base + (size_t)(kt * 64 + rr) * 64 + cc,
                    (char*)Ks + (i * 4 + wv) * 1024);
        }
        {
            // packed V transpose: 2 keys x 8 d's -> 8 u32 LDS writes,
            // conflict-free under the XOR swizzle.
            const u16* vsrc = V + base + (size_t)(kt * 64 + vkey) * 64 + vd0;
            uint4 va = *reinterpret_cast<const uint4*>(vsrc);
            uint4 vb = *reinterpret_cast<const uint4*>(vsrc + 64);
            u16 k0[8], k1[8];
            *reinterpret_cast<uint4*>(k0) = va;
            *reinterpret_cast<uint4*>(k1) = vb;
#pragma unroll
            for (int i = 0; i < 8; ++i) {
                int d = vd0 + i;
                int slot = (vkey >> 3) ^ (d & 7);
                u32 w = (u32)k0[i] | ((u32)k1[i] << 16);
                reinterpret_cast<u32*>(Vt)[(d * 64 + slot * 8 + (vkey & 7)) >> 1] = w;
            }
        }
        asm volatile("s_waitcnt vmcnt(0)" ::: "memory");
        __syncthreads();

        // S = Q K^T
        f32x4 sacc[4];
#pragma unroll
        for (int nf = 0; nf < 4; ++nf) sacc[nf] = z4;
#pragma unroll
        for (int kf = 0; kf < 2; ++kf) {
            int qr = wv * 16 + frow;
            int qc16 = (kf * 4 + fk8) ^ (qr & 7);
            bf16x8 aq = *reinterpret_cast<const bf16x8*>((char*)Qs + qr * 128 + qc16 * 16);
#pragma unroll
            for (int nf = 0; nf < 4; ++nf) {
                int kr = nf * 16 + frow;
                int kc16 = (kf * 4 + fk8) ^ (kr & 7);
                bf16x8 bk = *reinterpret_cast<const bf16x8*>((char*)Ks + kr * 128 + kc16 * 16);
                sacc[nf] = __builtin_amdgcn_mfma_f32_16x16x32_bf16(aq, bk, sacc[nf], 0, 0, 0);
            }
        }

        float sval[4][4], mx[4];
#pragma unroll
        for (int j = 0; j < 4; ++j) mx[j] = -1e30f;
#pragma unroll
        for (int nf = 0; nf < 4; ++nf) {
            float mval = mask[b * M_ + kt * 64 + nf * 16 + frow];
#pragma unroll
            for (int j = 0; j < 4; ++j) {
                float v = sacc[nf][j] * 0.125f + mval;
                sval[nf][j] = v;
                mx[j] = fmaxf(mx[j], v);
            }
        }
#pragma unroll
        for (int j = 0; j < 4; ++j) {
            float m = mx[j];
            m = fmaxf(m, __shfl_xor(m, 1));
            m = fmaxf(m, __shfl_xor(m, 2));
            m = fmaxf(m, __shfl_xor(m, 4));
            m = fmaxf(m, __shfl_xor(m, 8));
            float mnew = fmaxf(m_i[j], m);
            float c = __expf(m_i[j] - mnew);
            float rs = 0.f;
#pragma unroll
            for (int nf = 0; nf < 4; ++nf) {
                float p = __expf(sval[nf][j] - mnew);
                rs += p;
                Pl[wv * 1152 + (fk8 * 4 + j) * 72 + nf * 16 + frow] = f2bf(p);
            }
            rs += __shfl_xor(rs, 1);
            rs += __shfl_xor(rs, 2);
            rs += __shfl_xor(rs, 4);
            rs += __shfl_xor(rs, 8);
            l_i[j] = l_i[j] * c + rs;
            m_i[j] = mnew;
#pragma unroll
            for (int nf = 0; nf < 4; ++nf) o_acc[nf][j] *= c;
        }

        // O += P @ V
#pragma unroll
        for (int kf = 0; kf < 2; ++kf) {
            bf16x8 ap = *reinterpret_cast<const bf16x8*>(
                &Pl[wv * 1152 + frow * 72 + fk8 * 8 + kf * 32]);
#pragma unroll
            for (int nf = 0; nf < 4; ++nf) {
                int vr = nf * 16 + frow;
                int vc16 = (kf * 4 + fk8) ^ (vr & 7);
                bf16x8 bv = *reinterpret_cast<const bf16x8*>((char*)Vt + vr * 128 + vc16 * 16);
                o_acc[nf] = __builtin_amdgcn_mfma_f32_16x16x32_bf16(ap, bv, o_acc[nf], 0, 0, 0);
            }
        }
    }

#pragma unroll
    for (int j = 0; j < 4; ++j) {
        float inv = 1.f / l_i[j];
        int grow = qt * 64 + wv * 16 + fk8 * 4 + j;
        size_t obase = ((size_t)(b * M_ + grow)) * DM_ + h * 64;
#pragma unroll
        for (int nf = 0; nf < 4; ++nf)
            O[obase + nf * 16 + frow] = f2bf(o_acc[nf][j] * inv);
    }
}

// ---------------------------------------------------------------------------
// LN: out = LN(y + res + bias) * g + beta ; optional bf16 copy.  1 row/block.
// ---------------------------------------------------------------------------
template <bool WBF>
__global__ __launch_bounds__(256) void ln_kernel(const float* __restrict__ y,
                                                 const float* __restrict__ res,
                                                 const float* __restrict__ bias,
                                                 const float* __restrict__ g,
                                                 const float* __restrict__ beta,
                                                 float* __restrict__ outf,
                                                 u16* __restrict__ outb) {
    __shared__ float red[2][4];
    const int row = blockIdx.x, tid = threadIdx.x;
    const size_t base = (size_t)row * 1024 + tid * 4;
    float4 v = *reinterpret_cast<const float4*>(y + base);
    float4 r = *reinterpret_cast<const float4*>(res + base);
    float4 bb = *reinterpret_cast<const float4*>(bias + tid * 4);
    v.x += r.x + bb.x; v.y += r.y + bb.y; v.z += r.z + bb.z; v.w += r.w + bb.w;
    float sum = v.x + v.y + v.z + v.w;
    float sq = v.x * v.x + v.y * v.y + v.z * v.z + v.w * v.w;
#pragma unroll
    for (int off = 32; off; off >>= 1) {
        sum += __shfl_down(sum, off);
        sq += __shfl_down(sq, off);
    }
    if ((tid & 63) == 0) { red[0][tid >> 6] = sum; red[1][tid >> 6] = sq; }
    __syncthreads();
    sum = red[0][0] + red[0][1] + red[0][2] + red[0][3];
    sq = red[1][0] + red[1][1] + red[1][2] + red[1][3];
    float mu = sum * (1.f / 1024.f);
    float var = sq * (1.f / 1024.f) - mu * mu;
    float rstd = rsqrtf(var + 1e-12f);
    float4 gg = *reinterpret_cast<const float4*>(g + tid * 4);
    float4 be = *reinterpret_cast<const float4*>(beta + tid * 4);
    float4 o;
    o.x = (v.x - mu) * rstd * gg.x + be.x;
    o.y = (v.y - mu) * rstd * gg.y + be.y;
    o.z = (v.z - mu) * rstd * gg.z + be.z;
    o.w = (v.w - mu) * rstd * gg.w + be.w;
    *reinterpret_cast<float4*>(outf + base) = o;
    if (WBF) {
        unsigned long long p = (unsigned long long)f2bf(o.x)
                             | ((unsigned long long)f2bf(o.y) << 16)
                             | ((unsigned long long)f2bf(o.z) << 32)
                             | ((unsigned long long)f2bf(o.w) << 48);
        *reinterpret_cast<unsigned long long*>(outb + base) = p;
    }
}

// ---------------------------------------------------------------------------
extern "C" void kernel_launch(void* const* d_in, const int* in_sizes, int n_in,
                              void* d_out, int out_size, void* d_ws, size_t ws_size,
                              hipStream_t stream) {
    const float* x    = (const float*)d_in[0];
    const float* mask = (const float*)d_in[1];
    const float* Pq   = (const float*)d_in[2];
    const float* Vq   = (const float*)d_in[3];
    const float* bq   = (const float*)d_in[4];
    const float* Pk   = (const float*)d_in[5];
    const float* Vk   = (const float*)d_in[6];
    const float* bk   = (const float*)d_in[7];
    const float* Pv   = (const float*)d_in[8];
    const float* Vv   = (const float*)d_in[9];
    const float* bv   = (const float*)d_in[10];
    const float* Uo   = (const float*)d_in[11];
    const float* Vo   = (const float*)d_in[12];
    const float* bo   = (const float*)d_in[13];
    const float* g1   = (const float*)d_in[14];
    const float* be1  = (const float*)d_in[15];
    const float* U1   = (const float*)d_in[16];
    const float* V1   = (const float*)d_in[17];
    const float* b1   = (const float*)d_in[18];
    const float* U2   = (const float*)d_in[19];
    const float* V2   = (const float*)d_in[20];
    const float* b2   = (const float*)d_in[21];
    const float* g2   = (const float*)d_in[22];
    const float* be2  = (const float*)d_in[23];
    float* out = (float*)d_out;

    const size_t MB = 1048576;
    char* ws = (char*)d_ws;
    u16* Pt  = (u16*)(ws + 0);                 // 3 MB (1536 x 1024 bf16)
    u16* Ftq = (u16*)(ws + 3 * MB);            // 80 KB each (16x64x40)
    u16* Ftk = (u16*)(ws + 3 * MB + 131072);
    u16* Ftv = (u16*)(ws + 3 * MB + 262144);
    u16* Uot = (u16*)(ws + 4 * MB);            // 1 MB (512 x 1024)
    u16* Vot = (u16*)(ws + 5 * MB);            // 1 MB (1024 x 512)
    u16* U1t = (u16*)(ws + 6 * MB);            // 1 MB (512 x 1024)
    u16* V1t = (u16*)(ws + 7 * MB);            // 4 MB (4096 x 512)
    u16* U2t = (u16*)(ws + 11 * MB);           // 4 MB (512 x 4096)
    u16* V2t = (u16*)(ws + 15 * MB);           // 1 MB (1024 x 512)
    u16* Xb  = (u16*)(ws + 16 * MB);           // 16 MB (x bf16; later x1 bf16)
    u16* Tmp = (u16*)(ws + 32 * MB);           // 24 MB (8192 x 1536 bf16)
    u16* Qb  = (u16*)(ws + 56 * MB);           // 16 MB
    u16* Kb  = (u16*)(ws + 72 * MB);           // 16 MB
    u16* Vb  = (u16*)(ws + 88 * MB);           // 16 MB
    u16* Ob  = (u16*)(ws + 104 * MB);          // 16 MB
    u16* Hb  = (u16*)(ws + 32 * MB);           // 64 MB (reuses Tmp/Q/K/V)
    float* Yf = (float*)(ws + 56 * MB);        // 32 MB (reuses Q/K; then Hb tail)
    u16* Tb  = (u16*)(ws + 96 * MB);           // 8 MB (8192 x 512 bf16)
    float* X1f = (float*)(ws + 120 * MB);      // 32 MB ; end = 152 MB

    // --- precompute ---
    conv_bf16<<<8192, 256, 0, stream>>>(x, Xb);
    prep_p<<<dim3(16, 8), 256, 0, stream>>>(Pq, Pt);
    prep_p<<<dim3(16, 8), 256, 0, stream>>>(Pk, Pt + 512 * 1024);
    prep_p<<<dim3(16, 8), 256, 0, stream>>>(Pv, Pt + 1024 * 1024);
    prep_f<<<16, 256, 0, stream>>>(Vq, Ftq);
    prep_f<<<16, 256, 0, stream>>>(Vk, Ftk);
    prep_f<<<16, 256, 0, stream>>>(Vv, Ftv);
    transpose_w<<<dim3(8, 16), 256, 0, stream>>>(Uo, Uot, 1024, 512);
    transpose_w<<<dim3(16, 8), 256, 0, stream>>>(Vo, Vot, 512, 1024);
    transpose_w<<<dim3(8, 16), 256, 0, stream>>>(U1, U1t, 1024, 512);
    transpose_w<<<dim3(64, 8), 256, 0, stream>>>(V1, V1t, 512, 4096);
    transpose_w<<<dim3(8, 64), 256, 0, stream>>>(U2, U2t, 4096, 512);
    transpose_w<<<dim3(16, 8), 256, 0, stream>>>(V2, V2t, 512, 1024);

    // --- QKV: Tmp = x @ [Pq|Pk|Pv], then per-head rank-32 MFMA stage ---
    gemm_bf16<0, 4><<<dim3(12, 64), 256, 0, stream>>>(Xb, Pt, nullptr, Tmp, 1024, 1536);
    qkv_s2<<<dim3(128, 16), 256, 0, stream>>>(Tmp, Ftq, Ftk, Ftv, bq, bk, bv, Qb, Kb, Vb);

    // --- attention ---
    attn_mfma<<<2048, 256, 0, stream>>>(Qb, Kb, Vb, mask, Ob);

    // --- attn out proj + LN1 ---
    gemm_bf16<0, 2><<<dim3(8, 64), 256, 0, stream>>>(Ob, Uot, nullptr, Tb, 1024, 512);
    gemm_bf16<3, 4><<<dim3(8, 64), 256, 0, stream>>>(Tb, Vot, nullptr, Yf, 512, 1024);
    ln_kernel<true><<<8192, 256, 0, stream>>>(Yf, x, bo, g1, be1, X1f, Xb);

    // --- FFN + LN2 ---
    gemm_bf16<0, 2><<<dim3(8, 64), 256, 0, stream>>>(Xb, U1t, nullptr, Tb, 1024, 512);
    gemm_bf16<2, 4><<<dim3(32, 64), 256, 0, stream>>>(Tb, V1t, b1, Hb, 512, 4096);
    gemm_bf16<0, 2><<<dim3(8, 64), 256, 0, stream>>>(Hb, U2t, nullptr, Tb, 4096, 512);
    gemm_bf16<3, 4><<<dim3(8, 64), 256, 0, stream>>>(Tb, V2t, nullptr, Yf, 512, 1024);
    ln_kernel<false><<<8192, 256, 0, stream>>>(Yf, X1f, b2, g2, be2, out, nullptr);
}

// Round 4
// 378.788 us; speedup vs baseline: 11.0449x; 1.1020x over previous
//
#include <hip/hip_runtime.h>
#include <hip/hip_bf16.h>
#include <math.h>

typedef unsigned short u16;
typedef unsigned int u32;
typedef __attribute__((ext_vector_type(8))) short bf16x8;
typedef __attribute__((ext_vector_type(4))) float f32x4;

#define B_ 8
#define M_ 1024
#define DM_ 1024
#define H_ 16
#define DH_ 64
#define NR_ 8192

__device__ __forceinline__ u16 f2bf(float f) {
    unsigned u = __float_as_uint(f);
    u += 0x7FFFu + ((u >> 16) & 1u);
    return (u16)(u >> 16);
}

__device__ __forceinline__ void gload16(const void* g, void* l) {
    __builtin_amdgcn_global_load_lds(
        (const __attribute__((address_space(1))) void*)g,
        (__attribute__((address_space(3))) void*)l, 16, 0, 0);
}

// ---------------------------------------------------------------------------
// x (f32) -> bf16, vectorized
// ---------------------------------------------------------------------------
__global__ __launch_bounds__(256) void conv_bf16(const float* __restrict__ in,
                                                 u16* __restrict__ out) {
    int i = (blockIdx.x * 256 + threadIdx.x) * 4;
    float4 v = *reinterpret_cast<const float4*>(in + i);
    unsigned long long p = (unsigned long long)f2bf(v.x)
                         | ((unsigned long long)f2bf(v.y) << 16)
                         | ((unsigned long long)f2bf(v.z) << 32)
                         | ((unsigned long long)f2bf(v.w) << 48);
    *reinterpret_cast<unsigned long long*>(out + i) = p;
}

// ---------------------------------------------------------------------------
// Pt[(h*32+r)][k] = P[h][k][r]  bf16.  grid (16, 8): h, k-chunk 128.
// ---------------------------------------------------------------------------
__global__ __launch_bounds__(256) void prep_p(const float* __restrict__ P,
                                              u16* __restrict__ Pt) {
    __shared__ float Ps[128][33];
    const int h = blockIdx.x, kc = blockIdx.y * 128, tid = threadIdx.x;
#pragma unroll
    for (int i = 0; i < 16; ++i) {
        int e = tid + i * 256;
        int kk = e >> 5, r = e & 31;
        Ps[kk][r] = P[(size_t)h * 32768 + (size_t)(kc + kk) * 32 + r];
    }
    __syncthreads();
#pragma unroll
    for (int i = 0; i < 16; ++i) {
        int e = tid + i * 256;
        int r = e >> 7, k = e & 127;
        Pt[(size_t)(h * 32 + r) * 1024 + kc + k] = f2bf(Ps[k][r]);
    }
}

// ---------------------------------------------------------------------------
// Ft[h][e][r] = V[h][r][e]  bf16, row stride 40.  grid (16).
// ---------------------------------------------------------------------------
__global__ __launch_bounds__(256) void prep_f(const float* __restrict__ V,
                                              u16* __restrict__ Ft) {
    __shared__ float Vs[32][65];
    const int h = blockIdx.x, tid = threadIdx.x;
#pragma unroll
    for (int i = 0; i < 8; ++i) {
        int e = tid + i * 256;
        int r = e >> 6, c = e & 63;
        Vs[r][c] = V[(size_t)h * 2048 + r * 64 + c];
    }
    __syncthreads();
#pragma unroll
    for (int i = 0; i < 8; ++i) {
        int idx = tid + i * 256;
        int e = idx >> 5, r = idx & 31;
        Ft[(size_t)h * 2560 + e * 40 + r] = f2bf(Vs[r][e]);
    }
}

// ---------------------------------------------------------------------------
// transpose f32 (R x C) -> bf16 (C x R).  grid (C/64, R/64)
// ---------------------------------------------------------------------------
__global__ __launch_bounds__(256) void transpose_w(const float* __restrict__ in,
                                                   u16* __restrict__ out,
                                                   int R, int C) {
    __shared__ float t[64][65];
    const int rb = blockIdx.y * 64, cb = blockIdx.x * 64, tid = threadIdx.x;
#pragma unroll
    for (int i = 0; i < 16; ++i) {
        int e = tid + i * 256;
        int r = e >> 6, c = e & 63;
        t[r][c] = in[(size_t)(rb + r) * C + cb + c];
    }
    __syncthreads();
#pragma unroll
    for (int i = 0; i < 16; ++i) {
        int e = tid + i * 256;
        int r = e >> 6, c = e & 63;
        out[(size_t)(cb + r) * R + rb + c] = f2bf(t[c][r]);
    }
}

// ---------------------------------------------------------------------------
// bf16 MFMA GEMM (single-buffer): C(8192 x N) = A(8192 x K) @ Bt(N x K)^T
// BM=128, BN=NF*32, BK=64, 4 waves, global_load_lds + XOR swizzle, XCD remap.
// EPI: 0 bf16, 2 bias+gelu bf16, 3 f32.
// ---------------------------------------------------------------------------
template <int EPI, int NF>
__global__ __launch_bounds__(256) void gemm_bf16(const u16* __restrict__ A,
                                                 const u16* __restrict__ Bt,
                                                 const float* __restrict__ bias,
                                                 void* __restrict__ Cout,
                                                 int K, int N) {
    constexpr int BN = NF * 32;
    __shared__ u16 As[128 * 64];
    __shared__ u16 Bs[BN * 64];
    const int tid = threadIdx.x;
    const int lane = tid & 63, wv = tid >> 6;

    const int NX = gridDim.x;
    const int flat = blockIdx.x + blockIdx.y * NX;
    const int q = (NX * gridDim.y) >> 3;
    const int nid = (flat & 7) * q + (flat >> 3);
    const int row0 = (nid / NX) * 128, col0 = (nid % NX) * BN;

    const int frow = lane & 15, fk8 = lane >> 4;
    const int wm = (wv >> 1) * 64, wn = (wv & 1) * (BN / 2);

    f32x4 acc[4][NF];
    const f32x4 z4 = {0.f, 0.f, 0.f, 0.f};
#pragma unroll
    for (int i = 0; i < 4; ++i)
#pragma unroll
        for (int j = 0; j < NF; ++j) acc[i][j] = z4;

    for (int k0 = 0; k0 < K; k0 += 64) {
#pragma unroll
        for (int i = 0; i < 4; ++i) {
            int rr = (i * 4 + wv) * 8 + (lane >> 3);
            int cc = ((lane & 7) ^ (rr & 7)) * 8;
            gload16(A + (size_t)(row0 + rr) * K + k0 + cc,
                    (char*)As + (i * 4 + wv) * 1024);
        }
#pragma unroll
        for (int i = 0; i < NF; ++i) {
            int rr = (i * 4 + wv) * 8 + (lane >> 3);
            int cc = ((lane & 7) ^ (rr & 7)) * 8;
            gload16(Bt + (size_t)(col0 + rr) * K + k0 + cc,
                    (char*)Bs + (i * 4 + wv) * 1024);
        }
        asm volatile("s_waitcnt vmcnt(0)" ::: "memory");
        __syncthreads();
#pragma unroll
        for (int kf = 0; kf < 2; ++kf) {
            bf16x8 af[4], bfr[NF];
#pragma unroll
            for (int mf = 0; mf < 4; ++mf) {
                int r = wm + mf * 16 + frow;
                int c16 = (kf * 4 + fk8) ^ (r & 7);
                af[mf] = *reinterpret_cast<const bf16x8*>((char*)As + r * 128 + c16 * 16);
            }
#pragma unroll
            for (int nf = 0; nf < NF; ++nf) {
                int r = wn + nf * 16 + frow;
                int c16 = (kf * 4 + fk8) ^ (r & 7);
                bfr[nf] = *reinterpret_cast<const bf16x8*>((char*)Bs + r * 128 + c16 * 16);
            }
#pragma unroll
            for (int mf = 0; mf < 4; ++mf)
#pragma unroll
                for (int nf = 0; nf < NF; ++nf)
                    acc[mf][nf] = __builtin_amdgcn_mfma_f32_16x16x32_bf16(
                        af[mf], bfr[nf], acc[mf][nf], 0, 0, 0);
        }
        __syncthreads();
    }

    const int orow = fk8 * 4, ocol = frow;
#pragma unroll
    for (int mf = 0; mf < 4; ++mf)
#pragma unroll
        for (int nf = 0; nf < NF; ++nf)
#pragma unroll
            for (int j = 0; j < 4; ++j) {
                int row = row0 + wm + mf * 16 + orow + j;
                int col = col0 + wn + nf * 16 + ocol;
                float v = acc[mf][nf][j];
                if (EPI == 2) {
                    v += bias[col];
                    v = 0.5f * v * (1.f + erff(v * 0.70710678118f));
                    ((u16*)Cout)[(size_t)row * N + col] = f2bf(v);
                } else if (EPI == 3) {
                    ((float*)Cout)[(size_t)row * N + col] = v;
                } else {
                    ((u16*)Cout)[(size_t)row * N + col] = f2bf(v);
                }
            }
}

// ---------------------------------------------------------------------------
// Double-buffered prefetch GEMM for N=512 (NF=2, EPI=0).  One barrier per
// K-step; STAGE(next) issued after the barrier so HBM latency hides under
// the current tile's MFMA (catalog T3 minimum-2-phase).
// ---------------------------------------------------------------------------
__global__ __launch_bounds__(256) void gemm_db(const u16* __restrict__ A,
                                               const u16* __restrict__ Bt,
                                               u16* __restrict__ Cout,
                                               int K, int N) {
    __shared__ u16 As[2][128 * 64];
    __shared__ u16 Bs[2][64 * 64];
    const int tid = threadIdx.x;
    const int lane = tid & 63, wv = tid >> 6;

    const int NX = gridDim.x;
    const int flat = blockIdx.x + blockIdx.y * NX;
    const int q = (NX * gridDim.y) >> 3;
    const int nid = (flat & 7) * q + (flat >> 3);
    const int row0 = (nid / NX) * 128, col0 = (nid % NX) * 64;

    const int frow = lane & 15, fk8 = lane >> 4;
    const int wm = (wv >> 1) * 64, wn = (wv & 1) * 32;

    f32x4 acc[4][2];
    const f32x4 z4 = {0.f, 0.f, 0.f, 0.f};
#pragma unroll
    for (int i = 0; i < 4; ++i) {
        acc[i][0] = z4;
        acc[i][1] = z4;
    }

    const int srr = (lane >> 3);
    const int scc = (lane & 7);

    // prologue: stage tile 0 into buffer 0
#pragma unroll
    for (int i = 0; i < 4; ++i) {
        int rr = (i * 4 + wv) * 8 + srr;
        int cc = (scc ^ (rr & 7)) * 8;
        gload16(A + (size_t)(row0 + rr) * K + cc, (char*)&As[0][0] + (i * 4 + wv) * 1024);
    }
#pragma unroll
    for (int i = 0; i < 2; ++i) {
        int rr = (i * 4 + wv) * 8 + srr;
        int cc = (scc ^ (rr & 7)) * 8;
        gload16(Bt + (size_t)(col0 + rr) * K + cc, (char*)&Bs[0][0] + (i * 4 + wv) * 1024);
    }

    int cur = 0;
    for (int k0 = 0; k0 < K; k0 += 64) {
        __syncthreads();  // implicit vmcnt(0)+lgkmcnt(0): buf[cur] staged, prev reads done
        if (k0 + 64 < K) {
            int kn = k0 + 64;
#pragma unroll
            for (int i = 0; i < 4; ++i) {
                int rr = (i * 4 + wv) * 8 + srr;
                int cc = (scc ^ (rr & 7)) * 8;
                gload16(A + (size_t)(row0 + rr) * K + kn + cc,
                        (char*)&As[cur ^ 1][0] + (i * 4 + wv) * 1024);
            }
#pragma unroll
            for (int i = 0; i < 2; ++i) {
                int rr = (i * 4 + wv) * 8 + srr;
                int cc = (scc ^ (rr & 7)) * 8;
                gload16(Bt + (size_t)(col0 + rr) * K + kn + cc,
                        (char*)&Bs[cur ^ 1][0] + (i * 4 + wv) * 1024);
            }
        }
#pragma unroll
        for (int kf = 0; kf < 2; ++kf) {
            bf16x8 af[4], bfr[2];
#pragma unroll
            for (int mf = 0; mf < 4; ++mf) {
                int r = wm + mf * 16 + frow;
                int c16 = (kf * 4 + fk8) ^ (r & 7);
                af[mf] = *reinterpret_cast<const bf16x8*>((char*)&As[cur][0] + r * 128 + c16 * 16);
            }
#pragma unroll
            for (int nf = 0; nf < 2; ++nf) {
                int r = wn + nf * 16 + frow;
                int c16 = (kf * 4 + fk8) ^ (r & 7);
                bfr[nf] = *reinterpret_cast<const bf16x8*>((char*)&Bs[cur][0] + r * 128 + c16 * 16);
            }
#pragma unroll
            for (int mf = 0; mf < 4; ++mf)
#pragma unroll
                for (int nf = 0; nf < 2; ++nf)
                    acc[mf][nf] = __builtin_amdgcn_mfma_f32_16x16x32_bf16(
                        af[mf], bfr[nf], acc[mf][nf], 0, 0, 0);
        }
        cur ^= 1;
    }

#pragma unroll
    for (int mf = 0; mf < 4; ++mf)
#pragma unroll
        for (int nf = 0; nf < 2; ++nf)
#pragma unroll
            for (int j = 0; j < 4; ++j) {
                int row = row0 + wm + mf * 16 + fk8 * 4 + j;
                int col = col0 + wn + nf * 16 + frow;
                Cout[(size_t)row * N + col] = f2bf(acc[mf][nf][j]);
            }
}

// ---------------------------------------------------------------------------
// QKV stage 2 (rank-32 per-head MFMA).  grid (128, 16).
// ---------------------------------------------------------------------------
__global__ __launch_bounds__(256) void qkv_s2(const u16* __restrict__ Tmp,
                                              const u16* __restrict__ Ftq,
                                              const u16* __restrict__ Ftk,
                                              const u16* __restrict__ Ftv,
                                              const float* __restrict__ bq,
                                              const float* __restrict__ bk,
                                              const float* __restrict__ bv,
                                              u16* __restrict__ Q,
                                              u16* __restrict__ K,
                                              u16* __restrict__ V) {
    __shared__ u16 Ts[64 * 104];
    const int m0 = blockIdx.x * 64, h = blockIdx.y, tid = threadIdx.x;
    const int lane = tid & 63, wv = tid >> 6;
    const int frow = lane & 15, fk8 = lane >> 4;

    {
        const int row = tid >> 2, seg = tid & 3;
#pragma unroll
        for (int sect = 0; sect < 3; ++sect) {
            int off = sect * 512 + h * 32;
            uint4 v = *reinterpret_cast<const uint4*>(
                Tmp + (size_t)(m0 + row) * 1536 + off + seg * 8);
            *reinterpret_cast<uint4*>(&Ts[row * 104 + sect * 32 + seg * 8]) = v;
        }
    }
    __syncthreads();

    const u16* Fts[3] = {Ftq, Ftk, Ftv};
    const float* bs[3] = {bq, bk, bv};
    u16* outs[3] = {Q, K, V};

    f32x4 acc[3][4];
    const f32x4 z4 = {0.f, 0.f, 0.f, 0.f};
#pragma unroll
    for (int f = 0; f < 3; ++f) {
        bf16x8 a = *reinterpret_cast<const bf16x8*>(
            &Ts[(wv * 16 + frow) * 104 + f * 32 + fk8 * 8]);
#pragma unroll
        for (int nf = 0; nf < 4; ++nf) {
            int e = nf * 16 + frow;
            bf16x8 b = *reinterpret_cast<const bf16x8*>(
                Fts[f] + (size_t)h * 2560 + e * 40 + fk8 * 8);
            acc[f][nf] = __builtin_amdgcn_mfma_f32_16x16x32_bf16(a, b, z4, 0, 0, 0);
        }
    }

    const int bb = m0 >> 10;
#pragma unroll
    for (int f = 0; f < 3; ++f)
#pragma unroll
        for (int nf = 0; nf < 4; ++nf) {
            int e = nf * 16 + frow;
            float bias = bs[f][h * 64 + e];
#pragma unroll
            for (int j = 0; j < 4; ++j) {
                int m = m0 + wv * 16 + fk8 * 4 + j;
                outs[f][(((size_t)(bb * 16 + h) << 10) + (m & 1023)) * 64 + e] =
                    f2bf(acc[f][nf][j] + bias);
            }
        }
}

// ---------------------------------------------------------------------------
// MFMA flash attention, swapped QK^T (S^T = K·Q^T) so scores are row-local:
// lane (frow=q, fk8) holds S[q][nf*16+fk8*4+j].  Row max/sum = 2 shfls.
// Base-2 softmax, defer-max (THR=8), truncation-packed P, Q-frag hoist,
// setprio around MFMA.  grid 2048 (XCD remap), 4 waves.
// ---------------------------------------------------------------------------
__global__ __launch_bounds__(256) void attn_mfma(const u16* __restrict__ Q,
                                                 const u16* __restrict__ K,
                                                 const u16* __restrict__ V,
                                                 const float* __restrict__ mask,
                                                 u16* __restrict__ O) {
    __shared__ u16 Qs[64 * 64];
    __shared__ u16 Ks[64 * 64];
    __shared__ u16 Vt[64 * 64];       // [d][key], swizzled
    __shared__ u16 Pw[4 * 16 * 72];   // per-wave P rows [q][key]
    const int flat = blockIdx.x;
    const int nid = (flat & 7) * 256 + (flat >> 3);
    const int hb = nid >> 4, qt = nid & 15;
    const int b = hb >> 4, h = hb & 15;
    const int tid = threadIdx.x, lane = tid & 63, wv = tid >> 6;
    const int frow = lane & 15, fk8 = lane >> 4;
    const size_t base = (size_t)hb * 65536;
    const float LOG2E = 1.44269504089f;

#pragma unroll
    for (int i = 0; i < 2; ++i) {
        int rr = (i * 4 + wv) * 8 + (lane >> 3);
        int cc = ((lane & 7) ^ (rr & 7)) * 8;
        gload16(Q + base + (size_t)(qt * 64 + rr) * 64 + cc,
                (char*)Qs + (i * 4 + wv) * 1024);
    }
    asm volatile("s_waitcnt vmcnt(0)" ::: "memory");
    __syncthreads();

    // hoist Q fragments (B-operand of swapped QK^T): row = wave's q
    bf16x8 qfrag[2];
#pragma unroll
    for (int kf = 0; kf < 2; ++kf) {
        int qr = wv * 16 + frow;
        int qc16 = (kf * 4 + fk8) ^ (qr & 7);
        qfrag[kf] = *reinterpret_cast<const bf16x8*>((char*)Qs + qr * 128 + qc16 * 16);
    }

    float m_i = -1e30f, l_i = 0.f;
    const f32x4 z4 = {0.f, 0.f, 0.f, 0.f};
    f32x4 o_acc[4];
#pragma unroll
    for (int nf = 0; nf < 4; ++nf) o_acc[nf] = z4;

    const int vkey = (tid & 31) * 2, vd0 = (tid >> 5) * 8;
    u32* pw32 = reinterpret_cast<u32*>(Pw);

    for (int kt = 0; kt < 16; ++kt) {
        __syncthreads();
#pragma unroll
        for (int i = 0; i < 2; ++i) {
            int rr = (i * 4 + wv) * 8 + (lane >> 3);
            int cc = ((lane & 7) ^ (rr & 7)) * 8;
            gload16(K + base + (size_t)(kt * 64 + rr) * 64 + cc,
                    (char*)Ks + (i * 4 + wv) * 1024);
        }
        {
            const u16* vsrc = V + base + (size_t)(kt * 64 + vkey) * 64 + vd0;
            uint4 va = *reinterpret_cast<const uint4*>(vsrc);
            uint4 vb = *reinterpret_cast<const uint4*>(vsrc + 64);
            u16 k0[8], k1[8];
            *reinterpret_cast<uint4*>(k0) = va;
            *reinterpret_cast<uint4*>(k1) = vb;
#pragma unroll
            for (int i = 0; i < 8; ++i) {
                int d = vd0 + i;
                int slot = (vkey >> 3) ^ (d & 7);
                u32 w = (u32)k0[i] | ((u32)k1[i] << 16);
                reinterpret_cast<u32*>(Vt)[(d * 64 + slot * 8 + (vkey & 7)) >> 1] = w;
            }
        }
        asm volatile("s_waitcnt vmcnt(0)" ::: "memory");
        __syncthreads();

        // S^T = K · Q^T : lane holds S[q=frow][key = nf*16 + fk8*4 + j]
        f32x4 sacc[4];
#pragma unroll
        for (int nf = 0; nf < 4; ++nf) sacc[nf] = z4;
        __builtin_amdgcn_s_setprio(1);
#pragma unroll
        for (int kf = 0; kf < 2; ++kf) {
#pragma unroll
            for (int nf = 0; nf < 4; ++nf) {
                int kr = nf * 16 + frow;
                int kc16 = (kf * 4 + fk8) ^ (kr & 7);
                bf16x8 ak = *reinterpret_cast<const bf16x8*>((char*)Ks + kr * 128 + kc16 * 16);
                sacc[nf] = __builtin_amdgcn_mfma_f32_16x16x32_bf16(ak, qfrag[kf], sacc[nf], 0, 0, 0);
            }
        }
        __builtin_amdgcn_s_setprio(0);

        // scale + mask (t in natural-log domain), row max via 2 shfls
        float tval[4][4];
        float tmax = -1e30f;
#pragma unroll
        for (int nf = 0; nf < 4; ++nf) {
            float4 mk = *reinterpret_cast<const float4*>(
                mask + b * M_ + kt * 64 + nf * 16 + fk8 * 4);
            float t0 = fmaf(sacc[nf][0], 0.125f, mk.x);
            float t1 = fmaf(sacc[nf][1], 0.125f, mk.y);
            float t2 = fmaf(sacc[nf][2], 0.125f, mk.z);
            float t3 = fmaf(sacc[nf][3], 0.125f, mk.w);
            tval[nf][0] = t0; tval[nf][1] = t1; tval[nf][2] = t2; tval[nf][3] = t3;
            tmax = fmaxf(tmax, fmaxf(fmaxf(t0, t1), fmaxf(t2, t3)));
        }
        tmax = fmaxf(tmax, __shfl_xor(tmax, 16));
        tmax = fmaxf(tmax, __shfl_xor(tmax, 32));

        // defer-max: rescale only when tile max exceeds running max by >8
        if (__any(tmax > m_i + 8.f)) {
            float mnew = fmaxf(m_i, tmax);
            float c = exp2f((m_i - mnew) * LOG2E);
            m_i = mnew;
            l_i *= c;
#pragma unroll
            for (int j = 0; j < 4; ++j) {
                float cj = __shfl(c, fk8 * 4 + j);
#pragma unroll
                for (int nf = 0; nf < 4; ++nf) o_acc[nf][j] *= cj;
            }
        }

        const float ml = m_i * LOG2E;
        float rs = 0.f;
#pragma unroll
        for (int nf = 0; nf < 4; ++nf) {
            float p0 = exp2f(fmaf(tval[nf][0], LOG2E, -ml));
            float p1 = exp2f(fmaf(tval[nf][1], LOG2E, -ml));
            float p2 = exp2f(fmaf(tval[nf][2], LOG2E, -ml));
            float p3 = exp2f(fmaf(tval[nf][3], LOG2E, -ml));
            rs += (p0 + p1) + (p2 + p3);
            u32 w0 = (__float_as_uint(p0) >> 16) | (__float_as_uint(p1) & 0xFFFF0000u);
            u32 w1 = (__float_as_uint(p2) >> 16) | (__float_as_uint(p3) & 0xFFFF0000u);
            int pidx = wv * 576 + frow * 36 + nf * 8 + fk8 * 2;
            pw32[pidx] = w0;
            pw32[pidx + 1] = w1;
        }
        rs += __shfl_xor(rs, 16);
        rs += __shfl_xor(rs, 32);
        l_i += rs;

        // O^acc += P @ V
        __builtin_amdgcn_s_setprio(1);
#pragma unroll
        for (int kf = 0; kf < 2; ++kf) {
            bf16x8 ap = *reinterpret_cast<const bf16x8*>(
                (char*)Pw + wv * 2304 + frow * 144 + kf * 64 + fk8 * 16);
#pragma unroll
            for (int nf = 0; nf < 4; ++nf) {
                int vr = nf * 16 + frow;
                int vc16 = (kf * 4 + fk8) ^ (vr & 7);
                bf16x8 bv = *reinterpret_cast<const bf16x8*>((char*)Vt + vr * 128 + vc16 * 16);
                o_acc[nf] = __builtin_amdgcn_mfma_f32_16x16x32_bf16(ap, bv, o_acc[nf], 0, 0, 0);
            }
        }
        __builtin_amdgcn_s_setprio(0);
    }

    // epilogue: per-output-row l via 4 shfls, normalize, store
#pragma unroll
    for (int j = 0; j < 4; ++j) {
        float lq = __shfl(l_i, fk8 * 4 + j);
        float inv = 1.f / lq;
        int grow = qt * 64 + wv * 16 + fk8 * 4 + j;
        size_t obase = ((size_t)(b * M_ + grow)) * DM_ + h * 64;
#pragma unroll
        for (int nf = 0; nf < 4; ++nf)
            O[obase + nf * 16 + frow] = f2bf(o_acc[nf][j] * inv);
    }
}

// ---------------------------------------------------------------------------
// LN: out = LN(y + res + bias) * g + beta ; optional bf16 copy.  1 row/block.
// ---------------------------------------------------------------------------
template <bool WBF>
__global__ __launch_bounds__(256) void ln_kernel(const float* __restrict__ y,
                                                 const float* __restrict__ res,
                                                 const float* __restrict__ bias,
                                                 const float* __restrict__ g,
                                                 const float* __restrict__ beta,
                                                 float* __restrict__ outf,
                                                 u16* __restrict__ outb) {
    __shared__ float red[2][4];
    const int row = blockIdx.x, tid = threadIdx.x;
    const size_t base = (size_t)row * 1024 + tid * 4;
    float4 v = *reinterpret_cast<const float4*>(y + base);
    float4 r = *reinterpret_cast<const float4*>(res + base);
    float4 bb = *reinterpret_cast<const float4*>(bias + tid * 4);
    v.x += r.x + bb.x; v.y += r.y + bb.y; v.z += r.z + bb.z; v.w += r.w + bb.w;
    float sum = v.x + v.y + v.z + v.w;
    float sq = v.x * v.x + v.y * v.y + v.z * v.z + v.w * v.w;
#pragma unroll
    for (int off = 32; off; off >>= 1) {
        sum += __shfl_down(sum, off);
        sq += __shfl_down(sq, off);
    }
    if ((tid & 63) == 0) { red[0][tid >> 6] = sum; red[1][tid >> 6] = sq; }
    __syncthreads();
    sum = red[0][0] + red[0][1] + red[0][2] + red[0][3];
    sq = red[1][0] + red[1][1] + red[1][2] + red[1][3];
    float mu = sum * (1.f / 1024.f);
    float var = sq * (1.f / 1024.f) - mu * mu;
    float rstd = rsqrtf(var + 1e-12f);
    float4 gg = *reinterpret_cast<const float4*>(g + tid * 4);
    float4 be = *reinterpret_cast<const float4*>(beta + tid * 4);
    float4 o;
    o.x = (v.x - mu) * rstd * gg.x + be.x;
    o.y = (v.y - mu) * rstd * gg.y + be.y;
    o.z = (v.z - mu) * rstd * gg.z + be.z;
    o.w = (v.w - mu) * rstd * gg.w + be.w;
    *reinterpret_cast<float4*>(outf + base) = o;
    if (WBF) {
        unsigned long long p = (unsigned long long)f2bf(o.x)
                             | ((unsigned long long)f2bf(o.y) << 16)
                             | ((unsigned long long)f2bf(o.z) << 32)
                             | ((unsigned long long)f2bf(o.w) << 48);
        *reinterpret_cast<unsigned long long*>(outb + base) = p;
    }
}

// ---------------------------------------------------------------------------
extern "C" void kernel_launch(void* const* d_in, const int* in_sizes, int n_in,
                              void* d_out, int out_size, void* d_ws, size_t ws_size,
                              hipStream_t stream) {
    const float* x    = (const float*)d_in[0];
    const float* mask = (const float*)d_in[1];
    const float* Pq   = (const float*)d_in[2];
    const float* Vq   = (const float*)d_in[3];
    const float* bq   = (const float*)d_in[4];
    const float* Pk   = (const float*)d_in[5];
    const float* Vk   = (const float*)d_in[6];
    const float* bk   = (const float*)d_in[7];
    const float* Pv   = (const float*)d_in[8];
    const float* Vv   = (const float*)d_in[9];
    const float* bv   = (const float*)d_in[10];
    const float* Uo   = (const float*)d_in[11];
    const float* Vo   = (const float*)d_in[12];
    const float* bo   = (const float*)d_in[13];
    const float* g1   = (const float*)d_in[14];
    const float* be1  = (const float*)d_in[15];
    const float* U1   = (const float*)d_in[16];
    const float* V1   = (const float*)d_in[17];
    const float* b1   = (const float*)d_in[18];
    const float* U2   = (const float*)d_in[19];
    const float* V2   = (const float*)d_in[20];
    const float* b2   = (const float*)d_in[21];
    const float* g2   = (const float*)d_in[22];
    const float* be2  = (const float*)d_in[23];
    float* out = (float*)d_out;

    const size_t MB = 1048576;
    char* ws = (char*)d_ws;
    u16* Pt  = (u16*)(ws + 0);                 // 3 MB (1536 x 1024 bf16)
    u16* Ftq = (u16*)(ws + 3 * MB);
    u16* Ftk = (u16*)(ws + 3 * MB + 131072);
    u16* Ftv = (u16*)(ws + 3 * MB + 262144);
    u16* Uot = (u16*)(ws + 4 * MB);            // 1 MB (512 x 1024)
    u16* Vot = (u16*)(ws + 5 * MB);            // 1 MB (1024 x 512)
    u16* U1t = (u16*)(ws + 6 * MB);            // 1 MB (512 x 1024)
    u16* V1t = (u16*)(ws + 7 * MB);            // 4 MB (4096 x 512)
    u16* U2t = (u16*)(ws + 11 * MB);           // 4 MB (512 x 4096)
    u16* V2t = (u16*)(ws + 15 * MB);           // 1 MB (1024 x 512)
    u16* Xb  = (u16*)(ws + 16 * MB);           // 16 MB (x bf16; later x1 bf16)
    u16* Tmp = (u16*)(ws + 32 * MB);           // 24 MB (8192 x 1536 bf16)
    u16* Qb  = (u16*)(ws + 56 * MB);           // 16 MB
    u16* Kb  = (u16*)(ws + 72 * MB);           // 16 MB
    u16* Vb  = (u16*)(ws + 88 * MB);           // 16 MB
    u16* Ob  = (u16*)(ws + 104 * MB);          // 16 MB
    u16* Hb  = (u16*)(ws + 32 * MB);           // 64 MB (reuses Tmp/Q/K/V)
    float* Yf = (float*)(ws + 56 * MB);        // 32 MB
    u16* Tb  = (u16*)(ws + 96 * MB);           // 8 MB (8192 x 512 bf16)
    float* X1f = (float*)(ws + 120 * MB);      // 32 MB ; end = 152 MB

    // --- precompute ---
    conv_bf16<<<8192, 256, 0, stream>>>(x, Xb);
    prep_p<<<dim3(16, 8), 256, 0, stream>>>(Pq, Pt);
    prep_p<<<dim3(16, 8), 256, 0, stream>>>(Pk, Pt + 512 * 1024);
    prep_p<<<dim3(16, 8), 256, 0, stream>>>(Pv, Pt + 1024 * 1024);
    prep_f<<<16, 256, 0, stream>>>(Vq, Ftq);
    prep_f<<<16, 256, 0, stream>>>(Vk, Ftk);
    prep_f<<<16, 256, 0, stream>>>(Vv, Ftv);
    transpose_w<<<dim3(8, 16), 256, 0, stream>>>(Uo, Uot, 1024, 512);
    transpose_w<<<dim3(16, 8), 256, 0, stream>>>(Vo, Vot, 512, 1024);
    transpose_w<<<dim3(8, 16), 256, 0, stream>>>(U1, U1t, 1024, 512);
    transpose_w<<<dim3(64, 8), 256, 0, stream>>>(V1, V1t, 512, 4096);
    transpose_w<<<dim3(8, 64), 256, 0, stream>>>(U2, U2t, 4096, 512);
    transpose_w<<<dim3(16, 8), 256, 0, stream>>>(V2, V2t, 512, 1024);

    // --- QKV ---
    gemm_bf16<0, 4><<<dim3(12, 64), 256, 0, stream>>>(Xb, Pt, nullptr, Tmp, 1024, 1536);
    qkv_s2<<<dim3(128, 16), 256, 0, stream>>>(Tmp, Ftq, Ftk, Ftv, bq, bk, bv, Qb, Kb, Vb);

    // --- attention ---
    attn_mfma<<<2048, 256, 0, stream>>>(Qb, Kb, Vb, mask, Ob);

    // --- attn out proj + LN1 ---
    gemm_db<<<dim3(8, 64), 256, 0, stream>>>(Ob, Uot, Tb, 1024, 512);
    gemm_bf16<3, 4><<<dim3(8, 64), 256, 0, stream>>>(Tb, Vot, nullptr, Yf, 512, 1024);
    ln_kernel<true><<<8192, 256, 0, stream>>>(Yf, x, bo, g1, be1, X1f, Xb);

    // --- FFN + LN2 ---
    gemm_db<<<dim3(8, 64), 256, 0, stream>>>(Xb, U1t, Tb, 1024, 512);
    gemm_bf16<2, 4><<<dim3(32, 64), 256, 0, stream>>>(Tb, V1t, b1, Hb, 512, 4096);
    gemm_db<<<dim3(8, 64), 256, 0, stream>>>(Hb, U2t, Tb, 4096, 512);
    gemm_bf16<3, 4><<<dim3(8, 64), 256, 0, stream>>>(Tb, V2t, nullptr, Yf, 512, 1024);
    ln_kernel<false><<<8192, 256, 0, stream>>>(Yf, X1f, b2, g2, be2, out, nullptr);
}

// Round 5
// 347.455 us; speedup vs baseline: 12.0409x; 1.0902x over previous
//
#include <hip/hip_runtime.h>
#include <hip/hip_bf16.h>
#include <math.h>

typedef unsigned short u16;
typedef unsigned int u32;
typedef __attribute__((ext_vector_type(8))) short bf16x8;
typedef __attribute__((ext_vector_type(4))) float f32x4;
typedef __attribute__((ext_vector_type(2))) unsigned int u32x2;
typedef __attribute__((ext_vector_type(4))) unsigned int u32x4;

#define B_ 8
#define M_ 1024
#define DM_ 1024
#define H_ 16
#define DH_ 64
#define NR_ 8192

__device__ __forceinline__ u16 f2bf(float f) {
    unsigned u = __float_as_uint(f);
    u += 0x7FFFu + ((u >> 16) & 1u);
    return (u16)(u >> 16);
}

__device__ __forceinline__ void gload16(const void* g, void* l) {
    __builtin_amdgcn_global_load_lds(
        (const __attribute__((address_space(1))) void*)g,
        (__attribute__((address_space(3))) void*)l, 16, 0, 0);
}

__device__ __forceinline__ u32 lds_addr(const void* p) {
    return (u32)(uintptr_t)(const __attribute__((address_space(3))) void*)p;
}

// ---------------------------------------------------------------------------
// Mega-prep: one launch does x->bf16, P transposes, V-factor transposes, and
// all 6 weight transposes.  Branch on blockIdx range (block-uniform).
// grid 4016, block 256.
// ---------------------------------------------------------------------------
__device__ void conv_dev(const float* __restrict__ in, u16* __restrict__ out,
                         int bid, int tid) {
#pragma unroll
    for (int j = 0; j < 4; ++j) {
        int i = bid * 4096 + j * 1024 + tid * 4;
        float4 v = *reinterpret_cast<const float4*>(in + i);
        unsigned long long p = (unsigned long long)f2bf(v.x)
                             | ((unsigned long long)f2bf(v.y) << 16)
                             | ((unsigned long long)f2bf(v.z) << 32)
                             | ((unsigned long long)f2bf(v.w) << 48);
        *reinterpret_cast<unsigned long long*>(out + i) = p;
    }
}

__device__ void prep_p_dev(const float* __restrict__ P, u16* __restrict__ Pt,
                           int h, int kc, int tid, float* sm) {
    float (*Ps)[33] = (float(*)[33])sm;
#pragma unroll
    for (int i = 0; i < 16; ++i) {
        int e = tid + i * 256;
        int kk = e >> 5, r = e & 31;
        Ps[kk][r] = P[(size_t)h * 32768 + (size_t)(kc + kk) * 32 + r];
    }
    __syncthreads();
#pragma unroll
    for (int i = 0; i < 16; ++i) {
        int e = tid + i * 256;
        int r = e >> 7, k = e & 127;
        Pt[(size_t)(h * 32 + r) * 1024 + kc + k] = f2bf(Ps[k][r]);
    }
}

__device__ void prep_f_dev(const float* __restrict__ V, u16* __restrict__ Ft,
                           int h, int tid, float* sm) {
    float (*Vs)[65] = (float(*)[65])sm;
#pragma unroll
    for (int i = 0; i < 8; ++i) {
        int e = tid + i * 256;
        int r = e >> 6, c = e & 63;
        Vs[r][c] = V[(size_t)h * 2048 + r * 64 + c];
    }
    __syncthreads();
#pragma unroll
    for (int i = 0; i < 8; ++i) {
        int idx = tid + i * 256;
        int e = idx >> 5, r = idx & 31;
        Ft[(size_t)h * 2560 + e * 40 + r] = f2bf(Vs[r][e]);
    }
}

__device__ void transp_dev(const float* __restrict__ in, u16* __restrict__ out,
                           int R, int C, int bx, int by, int tid, float* sm) {
    float (*t)[65] = (float(*)[65])sm;
    const int rb = by * 64, cb = bx * 64;
#pragma unroll
    for (int i = 0; i < 16; ++i) {
        int e = tid + i * 256;
        int r = e >> 6, c = e & 63;
        t[r][c] = in[(size_t)(rb + r) * C + cb + c];
    }
    __syncthreads();
#pragma unroll
    for (int i = 0; i < 16; ++i) {
        int e = tid + i * 256;
        int r = e >> 6, c = e & 63;
        out[(size_t)(cb + r) * R + rb + c] = f2bf(t[c][r]);
    }
}

__global__ __launch_bounds__(256) void prep_all(
    const float* __restrict__ x,
    const float* __restrict__ Pq, const float* __restrict__ Pk, const float* __restrict__ Pv,
    const float* __restrict__ Vq, const float* __restrict__ Vk, const float* __restrict__ Vv,
    const float* __restrict__ Uo, const float* __restrict__ Vo,
    const float* __restrict__ U1, const float* __restrict__ V1,
    const float* __restrict__ U2, const float* __restrict__ V2,
    u16* __restrict__ Xb, u16* __restrict__ Pt,
    u16* __restrict__ Ftq, u16* __restrict__ Ftk, u16* __restrict__ Ftv,
    u16* __restrict__ Uot, u16* __restrict__ Vot,
    u16* __restrict__ U1t, u16* __restrict__ V1t,
    u16* __restrict__ U2t, u16* __restrict__ V2t) {
    __shared__ float smem[4224];
    const int bid = blockIdx.x, tid = threadIdx.x;
    if (bid < 2048) {
        conv_dev(x, Xb, bid, tid);
    } else if (bid < 2432) {
        int t = bid - 2048, which = t >> 7, tt = t & 127;
        const float* P = which == 0 ? Pq : (which == 1 ? Pk : Pv);
        prep_p_dev(P, Pt + (size_t)which * 524288, tt >> 3, (tt & 7) * 128, tid, smem);
    } else if (bid < 2480) {
        int t = bid - 2432, which = t >> 4;
        const float* V = which == 0 ? Vq : (which == 1 ? Vk : Vv);
        u16* F = which == 0 ? Ftq : (which == 1 ? Ftk : Ftv);
        prep_f_dev(V, F, t & 15, tid, smem);
    } else if (bid < 2608) {
        int t = bid - 2480;
        transp_dev(Uo, Uot, 1024, 512, t & 7, t >> 3, tid, smem);
    } else if (bid < 2736) {
        int t = bid - 2608;
        transp_dev(Vo, Vot, 512, 1024, t & 15, t >> 4, tid, smem);
    } else if (bid < 2864) {
        int t = bid - 2736;
        transp_dev(U1, U1t, 1024, 512, t & 7, t >> 3, tid, smem);
    } else if (bid < 3376) {
        int t = bid - 2864;
        transp_dev(V1, V1t, 512, 4096, t & 63, t >> 6, tid, smem);
    } else if (bid < 3888) {
        int t = bid - 3376;
        transp_dev(U2, U2t, 4096, 512, t & 7, t >> 3, tid, smem);
    } else {
        int t = bid - 3888;
        transp_dev(V2, V2t, 512, 1024, t & 15, t >> 4, tid, smem);
    }
}

// ---------------------------------------------------------------------------
// bf16 MFMA GEMM (single-buffer): C(8192 x N) = A(8192 x K) @ Bt(N x K)^T
// BM=128, BN=NF*32, BK=64, 4 waves, global_load_lds + XOR swizzle, XCD remap.
// EPI: 0 bf16, 2 bias+gelu bf16, 3 f32.
// ---------------------------------------------------------------------------
template <int EPI, int NF>
__global__ __launch_bounds__(256) void gemm_bf16(const u16* __restrict__ A,
                                                 const u16* __restrict__ Bt,
                                                 const float* __restrict__ bias,
                                                 void* __restrict__ Cout,
                                                 int K, int N) {
    constexpr int BN = NF * 32;
    __shared__ u16 As[128 * 64];
    __shared__ u16 Bs[BN * 64];
    const int tid = threadIdx.x;
    const int lane = tid & 63, wv = tid >> 6;

    const int NX = gridDim.x;
    const int flat = blockIdx.x + blockIdx.y * NX;
    const int q = (NX * gridDim.y) >> 3;
    const int nid = (flat & 7) * q + (flat >> 3);
    const int row0 = (nid / NX) * 128, col0 = (nid % NX) * BN;

    const int frow = lane & 15, fk8 = lane >> 4;
    const int wm = (wv >> 1) * 64, wn = (wv & 1) * (BN / 2);

    f32x4 acc[4][NF];
    const f32x4 z4 = {0.f, 0.f, 0.f, 0.f};
#pragma unroll
    for (int i = 0; i < 4; ++i)
#pragma unroll
        for (int j = 0; j < NF; ++j) acc[i][j] = z4;

    for (int k0 = 0; k0 < K; k0 += 64) {
#pragma unroll
        for (int i = 0; i < 4; ++i) {
            int rr = (i * 4 + wv) * 8 + (lane >> 3);
            int cc = ((lane & 7) ^ (rr & 7)) * 8;
            gload16(A + (size_t)(row0 + rr) * K + k0 + cc,
                    (char*)As + (i * 4 + wv) * 1024);
        }
#pragma unroll
        for (int i = 0; i < NF; ++i) {
            int rr = (i * 4 + wv) * 8 + (lane >> 3);
            int cc = ((lane & 7) ^ (rr & 7)) * 8;
            gload16(Bt + (size_t)(col0 + rr) * K + k0 + cc,
                    (char*)Bs + (i * 4 + wv) * 1024);
        }
        asm volatile("s_waitcnt vmcnt(0)" ::: "memory");
        __syncthreads();
#pragma unroll
        for (int kf = 0; kf < 2; ++kf) {
            bf16x8 af[4], bfr[NF];
#pragma unroll
            for (int mf = 0; mf < 4; ++mf) {
                int r = wm + mf * 16 + frow;
                int c16 = (kf * 4 + fk8) ^ (r & 7);
                af[mf] = *reinterpret_cast<const bf16x8*>((char*)As + r * 128 + c16 * 16);
            }
#pragma unroll
            for (int nf = 0; nf < NF; ++nf) {
                int r = wn + nf * 16 + frow;
                int c16 = (kf * 4 + fk8) ^ (r & 7);
                bfr[nf] = *reinterpret_cast<const bf16x8*>((char*)Bs + r * 128 + c16 * 16);
            }
#pragma unroll
            for (int mf = 0; mf < 4; ++mf)
#pragma unroll
                for (int nf = 0; nf < NF; ++nf)
                    acc[mf][nf] = __builtin_amdgcn_mfma_f32_16x16x32_bf16(
                        af[mf], bfr[nf], acc[mf][nf], 0, 0, 0);
        }
        __syncthreads();
    }

    const int orow = fk8 * 4, ocol = frow;
#pragma unroll
    for (int mf = 0; mf < 4; ++mf)
#pragma unroll
        for (int nf = 0; nf < NF; ++nf)
#pragma unroll
            for (int j = 0; j < 4; ++j) {
                int row = row0 + wm + mf * 16 + orow + j;
                int col = col0 + wn + nf * 16 + ocol;
                float v = acc[mf][nf][j];
                if (EPI == 2) {
                    v += bias[col];
                    v = 0.5f * v * (1.f + erff(v * 0.70710678118f));
                    ((u16*)Cout)[(size_t)row * N + col] = f2bf(v);
                } else if (EPI == 3) {
                    ((float*)Cout)[(size_t)row * N + col] = v;
                } else {
                    ((u16*)Cout)[(size_t)row * N + col] = f2bf(v);
                }
            }
}

// ---------------------------------------------------------------------------
// Double-buffered prefetch GEMM for N=512 outputs (BN=64, bf16 out).
// ---------------------------------------------------------------------------
__global__ __launch_bounds__(256) void gemm_db(const u16* __restrict__ A,
                                               const u16* __restrict__ Bt,
                                               u16* __restrict__ Cout,
                                               int K, int N) {
    __shared__ u16 As[2][128 * 64];
    __shared__ u16 Bs[2][64 * 64];
    const int tid = threadIdx.x;
    const int lane = tid & 63, wv = tid >> 6;

    const int NX = gridDim.x;
    const int flat = blockIdx.x + blockIdx.y * NX;
    const int q = (NX * gridDim.y) >> 3;
    const int nid = (flat & 7) * q + (flat >> 3);
    const int row0 = (nid / NX) * 128, col0 = (nid % NX) * 64;

    const int frow = lane & 15, fk8 = lane >> 4;
    const int wm = (wv >> 1) * 64, wn = (wv & 1) * 32;

    f32x4 acc[4][2];
    const f32x4 z4 = {0.f, 0.f, 0.f, 0.f};
#pragma unroll
    for (int i = 0; i < 4; ++i) {
        acc[i][0] = z4;
        acc[i][1] = z4;
    }

    const int srr = (lane >> 3);
    const int scc = (lane & 7);

#pragma unroll
    for (int i = 0; i < 4; ++i) {
        int rr = (i * 4 + wv) * 8 + srr;
        int cc = (scc ^ (rr & 7)) * 8;
        gload16(A + (size_t)(row0 + rr) * K + cc, (char*)&As[0][0] + (i * 4 + wv) * 1024);
    }
#pragma unroll
    for (int i = 0; i < 2; ++i) {
        int rr = (i * 4 + wv) * 8 + srr;
        int cc = (scc ^ (rr & 7)) * 8;
        gload16(Bt + (size_t)(col0 + rr) * K + cc, (char*)&Bs[0][0] + (i * 4 + wv) * 1024);
    }

    int cur = 0;
    for (int k0 = 0; k0 < K; k0 += 64) {
        __syncthreads();
        if (k0 + 64 < K) {
            int kn = k0 + 64;
#pragma unroll
            for (int i = 0; i < 4; ++i) {
                int rr = (i * 4 + wv) * 8 + srr;
                int cc = (scc ^ (rr & 7)) * 8;
                gload16(A + (size_t)(row0 + rr) * K + kn + cc,
                        (char*)&As[cur ^ 1][0] + (i * 4 + wv) * 1024);
            }
#pragma unroll
            for (int i = 0; i < 2; ++i) {
                int rr = (i * 4 + wv) * 8 + srr;
                int cc = (scc ^ (rr & 7)) * 8;
                gload16(Bt + (size_t)(col0 + rr) * K + kn + cc,
                        (char*)&Bs[cur ^ 1][0] + (i * 4 + wv) * 1024);
            }
        }
#pragma unroll
        for (int kf = 0; kf < 2; ++kf) {
            bf16x8 af[4], bfr[2];
#pragma unroll
            for (int mf = 0; mf < 4; ++mf) {
                int r = wm + mf * 16 + frow;
                int c16 = (kf * 4 + fk8) ^ (r & 7);
                af[mf] = *reinterpret_cast<const bf16x8*>((char*)&As[cur][0] + r * 128 + c16 * 16);
            }
#pragma unroll
            for (int nf = 0; nf < 2; ++nf) {
                int r = wn + nf * 16 + frow;
                int c16 = (kf * 4 + fk8) ^ (r & 7);
                bfr[nf] = *reinterpret_cast<const bf16x8*>((char*)&Bs[cur][0] + r * 128 + c16 * 16);
            }
#pragma unroll
            for (int mf = 0; mf < 4; ++mf)
#pragma unroll
                for (int nf = 0; nf < 2; ++nf)
                    acc[mf][nf] = __builtin_amdgcn_mfma_f32_16x16x32_bf16(
                        af[mf], bfr[nf], acc[mf][nf], 0, 0, 0);
        }
        cur ^= 1;
    }

#pragma unroll
    for (int mf = 0; mf < 4; ++mf)
#pragma unroll
        for (int nf = 0; nf < 2; ++nf)
#pragma unroll
            for (int j = 0; j < 4; ++j) {
                int row = row0 + wm + mf * 16 + fk8 * 4 + j;
                int col = col0 + wn + nf * 16 + frow;
                Cout[(size_t)row * N + col] = f2bf(acc[mf][nf][j]);
            }
}

// ---------------------------------------------------------------------------
// QKV stage 2 (rank-32 per-head MFMA).  grid (128, 16).
// ---------------------------------------------------------------------------
__global__ __launch_bounds__(256) void qkv_s2(const u16* __restrict__ Tmp,
                                              const u16* __restrict__ Ftq,
                                              const u16* __restrict__ Ftk,
                                              const u16* __restrict__ Ftv,
                                              const float* __restrict__ bq,
                                              const float* __restrict__ bk,
                                              const float* __restrict__ bv,
                                              u16* __restrict__ Q,
                                              u16* __restrict__ K,
                                              u16* __restrict__ V) {
    __shared__ u16 Ts[64 * 104];
    const int m0 = blockIdx.x * 64, h = blockIdx.y, tid = threadIdx.x;
    const int lane = tid & 63, wv = tid >> 6;
    const int frow = lane & 15, fk8 = lane >> 4;

    {
        const int row = tid >> 2, seg = tid & 3;
#pragma unroll
        for (int sect = 0; sect < 3; ++sect) {
            int off = sect * 512 + h * 32;
            uint4 v = *reinterpret_cast<const uint4*>(
                Tmp + (size_t)(m0 + row) * 1536 + off + seg * 8);
            *reinterpret_cast<uint4*>(&Ts[row * 104 + sect * 32 + seg * 8]) = v;
        }
    }
    __syncthreads();

    const u16* Fts[3] = {Ftq, Ftk, Ftv};
    const float* bs[3] = {bq, bk, bv};
    u16* outs[3] = {Q, K, V};

    f32x4 acc[3][4];
    const f32x4 z4 = {0.f, 0.f, 0.f, 0.f};
#pragma unroll
    for (int f = 0; f < 3; ++f) {
        bf16x8 a = *reinterpret_cast<const bf16x8*>(
            &Ts[(wv * 16 + frow) * 104 + f * 32 + fk8 * 8]);
#pragma unroll
        for (int nf = 0; nf < 4; ++nf) {
            int e = nf * 16 + frow;
            bf16x8 b = *reinterpret_cast<const bf16x8*>(
                Fts[f] + (size_t)h * 2560 + e * 40 + fk8 * 8);
            acc[f][nf] = __builtin_amdgcn_mfma_f32_16x16x32_bf16(a, b, z4, 0, 0, 0);
        }
    }

    const int bb = m0 >> 10;
#pragma unroll
    for (int f = 0; f < 3; ++f)
#pragma unroll
        for (int nf = 0; nf < 4; ++nf) {
            int e = nf * 16 + frow;
            float bias = bs[f][h * 64 + e];
#pragma unroll
            for (int j = 0; j < 4; ++j) {
                int m = m0 + wv * 16 + fk8 * 4 + j;
                outs[f][(((size_t)(bb * 16 + h) << 10) + (m & 1023)) * 64 + e] =
                    f2bf(acc[f][nf][j] + bias);
            }
        }
}

// ---------------------------------------------------------------------------
// MFMA flash attention.  Swapped QK^T; P via XOR-swizzled LDS (As-pattern) with
// v_perm truncation packs; V staged linearly into a [key/4][d/16][4][16]
// subtiled LDS and consumed via ds_read_b64_tr_b16 (T10).  Q staged through
// the K buffer and hoisted to registers.  grid 2048 (XCD remap), 4 waves.
// ---------------------------------------------------------------------------
__global__ __launch_bounds__(256) void attn_mfma(const u16* __restrict__ Q,
                                                 const u16* __restrict__ K,
                                                 const u16* __restrict__ V,
                                                 const float* __restrict__ mask,
                                                 u16* __restrict__ O) {
    __shared__ u16 Ks[4096];
    __shared__ u16 Vt[4096];
    __shared__ u16 Pw[4096];
    const int flat = blockIdx.x;
    const int nid = (flat & 7) * 256 + (flat >> 3);
    const int hb = nid >> 4, qt = nid & 15;
    const int b = hb >> 4, h = hb & 15;
    const int tid = threadIdx.x, lane = tid & 63, wv = tid >> 6;
    const int frow = lane & 15, fk8 = lane >> 4;
    const size_t base = (size_t)hb * 65536;
    const float LOG2E = 1.44269504089f;
    const int srr = lane >> 3, scc = lane & 7;

    // --- stage Q through Ks, hoist fragments ---
#pragma unroll
    for (int i = 0; i < 2; ++i) {
        int rr = (i * 4 + wv) * 8 + srr;
        int cc = (scc ^ (rr & 7)) * 8;
        gload16(Q + base + (size_t)(qt * 64 + rr) * 64 + cc,
                (char*)Ks + (i * 4 + wv) * 1024);
    }
    asm volatile("s_waitcnt vmcnt(0)" ::: "memory");
    __syncthreads();
    bf16x8 qfrag[2];
#pragma unroll
    for (int kf = 0; kf < 2; ++kf) {
        int qr = wv * 16 + frow;
        int c16 = (kf * 4 + fk8) ^ (qr & 7);
        qfrag[kf] = *reinterpret_cast<const bf16x8*>((char*)Ks + qr * 128 + c16 * 16);
    }

    // --- V staging source offsets (linear subtiled dest -> scattered src) ---
    int voff[2];
#pragma unroll
    for (int i = 0; i < 2; ++i) {
        int c = (i * 4 + wv) * 64 + lane;
        int kb = c >> 5, db = (c >> 3) & 3, kr = (c >> 1) & 3, hf = c & 1;
        voff[i] = (kb * 4 + kr) * 64 + db * 16 + hf * 8;
    }

    // --- tr-read per-lane base addrs (one per nf) ---
    u32 vta[4];
    {
        u32 vt0 = lds_addr(Vt) + fk8 * 1024 + frow * 2;
#pragma unroll
        for (int nf = 0; nf < 4; ++nf) vta[nf] = vt0 + nf * 128;
    }

    char* pwW = (char*)Pw + wv * 2048 + frow * 128 + (fk8 & 1) * 8;
    char* pwR = (char*)Pw + wv * 2048 + frow * 128;
    const float* mrow = mask + b * M_;

    float m_i = -1e30f, l_i = 0.f;
    const f32x4 z4 = {0.f, 0.f, 0.f, 0.f};
    f32x4 o_acc[4] = {z4, z4, z4, z4};

    for (int kt = 0; kt < 16; ++kt) {
        __syncthreads();
#pragma unroll
        for (int i = 0; i < 2; ++i) {
            int rr = (i * 4 + wv) * 8 + srr;
            int cc = (scc ^ (rr & 7)) * 8;
            gload16(K + base + (size_t)(kt * 64 + rr) * 64 + cc,
                    (char*)Ks + (i * 4 + wv) * 1024);
        }
#pragma unroll
        for (int i = 0; i < 2; ++i)
            gload16(V + base + kt * 4096 + voff[i], (char*)Vt + (i * 4 + wv) * 1024);
        asm volatile("s_waitcnt vmcnt(0)" ::: "memory");
        __syncthreads();

        // S^T = K · Q^T : lane holds S[q=frow][key = nf*16 + fk8*4 + j]
        f32x4 sacc[4] = {z4, z4, z4, z4};
        __builtin_amdgcn_s_setprio(1);
#pragma unroll
        for (int kf = 0; kf < 2; ++kf)
#pragma unroll
            for (int nf = 0; nf < 4; ++nf) {
                int kr = nf * 16 + frow;
                int c16 = (kf * 4 + fk8) ^ (kr & 7);
                bf16x8 ak = *reinterpret_cast<const bf16x8*>((char*)Ks + kr * 128 + c16 * 16);
                sacc[nf] = __builtin_amdgcn_mfma_f32_16x16x32_bf16(ak, qfrag[kf], sacc[nf], 0, 0, 0);
            }
        __builtin_amdgcn_s_setprio(0);

        float tval[4][4];
        float tmax = -1e30f;
#pragma unroll
        for (int nf = 0; nf < 4; ++nf) {
            float4 mk = *reinterpret_cast<const float4*>(mrow + kt * 64 + nf * 16 + fk8 * 4);
            float t0 = fmaf(sacc[nf][0], 0.125f, mk.x);
            float t1 = fmaf(sacc[nf][1], 0.125f, mk.y);
            float t2 = fmaf(sacc[nf][2], 0.125f, mk.z);
            float t3 = fmaf(sacc[nf][3], 0.125f, mk.w);
            tval[nf][0] = t0; tval[nf][1] = t1; tval[nf][2] = t2; tval[nf][3] = t3;
            tmax = fmaxf(tmax, fmaxf(fmaxf(t0, t1), fmaxf(t2, t3)));
        }
        tmax = fmaxf(tmax, __shfl_xor(tmax, 16));
        tmax = fmaxf(tmax, __shfl_xor(tmax, 32));

        if (__any(tmax > m_i + 8.f)) {
            float mnew = fmaxf(m_i, tmax);
            float c = exp2f((m_i - mnew) * LOG2E);
            m_i = mnew;
            l_i *= c;
#pragma unroll
            for (int j = 0; j < 4; ++j) {
                float cj = __shfl(c, fk8 * 4 + j);
#pragma unroll
                for (int nf = 0; nf < 4; ++nf) o_acc[nf][j] *= cj;
            }
        }

        const float ml = m_i * LOG2E;
        float rs = 0.f;
#pragma unroll
        for (int nf = 0; nf < 4; ++nf) {
            float p0 = exp2f(fmaf(tval[nf][0], LOG2E, -ml));
            float p1 = exp2f(fmaf(tval[nf][1], LOG2E, -ml));
            float p2 = exp2f(fmaf(tval[nf][2], LOG2E, -ml));
            float p3 = exp2f(fmaf(tval[nf][3], LOG2E, -ml));
            rs += (p0 + p1) + (p2 + p3);
            u32 w0 = __builtin_amdgcn_perm(__float_as_uint(p1), __float_as_uint(p0), 0x07060302u);
            u32 w1 = __builtin_amdgcn_perm(__float_as_uint(p3), __float_as_uint(p2), 0x07060302u);
            u32x2 wp = {w0, w1};
            *reinterpret_cast<u32x2*>(pwW + (((nf * 2 + (fk8 >> 1)) ^ (frow & 7)) * 16)) = wp;
        }
        rs += __shfl_xor(rs, 16);
        rs += __shfl_xor(rs, 32);
        l_i += rs;

        // O += P @ V  (A = P rows from swizzled LDS, B = V via tr-reads)
#pragma unroll
        for (int kf = 0; kf < 2; ++kf) {
            bf16x8 ap = *reinterpret_cast<const bf16x8*>(pwR + (((kf * 4 + fk8) ^ (frow & 7)) * 16));
            u32x2 r0, r1, r2, r3, r4, r5, r6, r7;
            if (kf == 0) {
                asm volatile("ds_read_b64_tr_b16 %0, %1" : "=&v"(r0) : "v"(vta[0]));
                asm volatile("ds_read_b64_tr_b16 %0, %1 offset:512" : "=&v"(r1) : "v"(vta[0]));
                asm volatile("ds_read_b64_tr_b16 %0, %1" : "=&v"(r2) : "v"(vta[1]));
                asm volatile("ds_read_b64_tr_b16 %0, %1 offset:512" : "=&v"(r3) : "v"(vta[1]));
                asm volatile("ds_read_b64_tr_b16 %0, %1" : "=&v"(r4) : "v"(vta[2]));
                asm volatile("ds_read_b64_tr_b16 %0, %1 offset:512" : "=&v"(r5) : "v"(vta[2]));
                asm volatile("ds_read_b64_tr_b16 %0, %1" : "=&v"(r6) : "v"(vta[3]));
                asm volatile("ds_read_b64_tr_b16 %0, %1 offset:512" : "=&v"(r7) : "v"(vta[3]));
            } else {
                asm volatile("ds_read_b64_tr_b16 %0, %1 offset:4096" : "=&v"(r0) : "v"(vta[0]));
                asm volatile("ds_read_b64_tr_b16 %0, %1 offset:4608" : "=&v"(r1) : "v"(vta[0]));
                asm volatile("ds_read_b64_tr_b16 %0, %1 offset:4096" : "=&v"(r2) : "v"(vta[1]));
                asm volatile("ds_read_b64_tr_b16 %0, %1 offset:4608" : "=&v"(r3) : "v"(vta[1]));
                asm volatile("ds_read_b64_tr_b16 %0, %1 offset:4096" : "=&v"(r4) : "v"(vta[2]));
                asm volatile("ds_read_b64_tr_b16 %0, %1 offset:4608" : "=&v"(r5) : "v"(vta[2]));
                asm volatile("ds_read_b64_tr_b16 %0, %1 offset:4096" : "=&v"(r6) : "v"(vta[3]));
                asm volatile("ds_read_b64_tr_b16 %0, %1 offset:4608" : "=&v"(r7) : "v"(vta[3]));
            }
            asm volatile("s_waitcnt lgkmcnt(0)" ::: "memory");
            __builtin_amdgcn_sched_barrier(0);
            __builtin_amdgcn_s_setprio(1);
            {
                u32x4 vv = {r0.x, r0.y, r1.x, r1.y};
                bf16x8 f; __builtin_memcpy(&f, &vv, 16);
                o_acc[0] = __builtin_amdgcn_mfma_f32_16x16x32_bf16(ap, f, o_acc[0], 0, 0, 0);
            }
            {
                u32x4 vv = {r2.x, r2.y, r3.x, r3.y};
                bf16x8 f; __builtin_memcpy(&f, &vv, 16);
                o_acc[1] = __builtin_amdgcn_mfma_f32_16x16x32_bf16(ap, f, o_acc[1], 0, 0, 0);
            }
            {
                u32x4 vv = {r4.x, r4.y, r5.x, r5.y};
                bf16x8 f; __builtin_memcpy(&f, &vv, 16);
                o_acc[2] = __builtin_amdgcn_mfma_f32_16x16x32_bf16(ap, f, o_acc[2], 0, 0, 0);
            }
            {
                u32x4 vv = {r6.x, r6.y, r7.x, r7.y};
                bf16x8 f; __builtin_memcpy(&f, &vv, 16);
                o_acc[3] = __builtin_amdgcn_mfma_f32_16x16x32_bf16(ap, f, o_acc[3], 0, 0, 0);
            }
            __builtin_amdgcn_s_setprio(0);
        }
    }

    // epilogue
#pragma unroll
    for (int j = 0; j < 4; ++j) {
        float lq = __shfl(l_i, fk8 * 4 + j);
        float inv = 1.f / lq;
        int grow = qt * 64 + wv * 16 + fk8 * 4 + j;
        size_t obase = ((size_t)(b * M_ + grow)) * DM_ + h * 64;
#pragma unroll
        for (int nf = 0; nf < 4; ++nf)
            O[obase + nf * 16 + frow] = f2bf(o_acc[nf][j] * inv);
    }
}

// ---------------------------------------------------------------------------
// LN: out = LN(y + res + bias) * g + beta ; optional bf16 copy.  1 row/block.
// ---------------------------------------------------------------------------
template <bool WBF>
__global__ __launch_bounds__(256) void ln_kernel(const float* __restrict__ y,
                                                 const float* __restrict__ res,
                                                 const float* __restrict__ bias,
                                                 const float* __restrict__ g,
                                                 const float* __restrict__ beta,
                                                 float* __restrict__ outf,
                                                 u16* __restrict__ outb) {
    __shared__ float red[2][4];
    const int row = blockIdx.x, tid = threadIdx.x;
    const size_t base = (size_t)row * 1024 + tid * 4;
    float4 v = *reinterpret_cast<const float4*>(y + base);
    float4 r = *reinterpret_cast<const float4*>(res + base);
    float4 bb = *reinterpret_cast<const float4*>(bias + tid * 4);
    v.x += r.x + bb.x; v.y += r.y + bb.y; v.z += r.z + bb.z; v.w += r.w + bb.w;
    float sum = v.x + v.y + v.z + v.w;
    float sq = v.x * v.x + v.y * v.y + v.z * v.z + v.w * v.w;
#pragma unroll
    for (int off = 32; off; off >>= 1) {
        sum += __shfl_down(sum, off);
        sq += __shfl_down(sq, off);
    }
    if ((tid & 63) == 0) { red[0][tid >> 6] = sum; red[1][tid >> 6] = sq; }
    __syncthreads();
    sum = red[0][0] + red[0][1] + red[0][2] + red[0][3];
    sq = red[1][0] + red[1][1] + red[1][2] + red[1][3];
    float mu = sum * (1.f / 1024.f);
    float var = sq * (1.f / 1024.f) - mu * mu;
    float rstd = rsqrtf(var + 1e-12f);
    float4 gg = *reinterpret_cast<const float4*>(g + tid * 4);
    float4 be = *reinterpret_cast<const float4*>(beta + tid * 4);
    float4 o;
    o.x = (v.x - mu) * rstd * gg.x + be.x;
    o.y = (v.y - mu) * rstd * gg.y + be.y;
    o.z = (v.z - mu) * rstd * gg.z + be.z;
    o.w = (v.w - mu) * rstd * gg.w + be.w;
    *reinterpret_cast<float4*>(outf + base) = o;
    if (WBF) {
        unsigned long long p = (unsigned long long)f2bf(o.x)
                             | ((unsigned long long)f2bf(o.y) << 16)
                             | ((unsigned long long)f2bf(o.z) << 32)
                             | ((unsigned long long)f2bf(o.w) << 48);
        *reinterpret_cast<unsigned long long*>(outb + base) = p;
    }
}

// ---------------------------------------------------------------------------
extern "C" void kernel_launch(void* const* d_in, const int* in_sizes, int n_in,
                              void* d_out, int out_size, void* d_ws, size_t ws_size,
                              hipStream_t stream) {
    const float* x    = (const float*)d_in[0];
    const float* mask = (const float*)d_in[1];
    const float* Pq   = (const float*)d_in[2];
    const float* Vq   = (const float*)d_in[3];
    const float* bq   = (const float*)d_in[4];
    const float* Pk   = (const float*)d_in[5];
    const float* Vk   = (const float*)d_in[6];
    const float* bk   = (const float*)d_in[7];
    const float* Pv   = (const float*)d_in[8];
    const float* Vv   = (const float*)d_in[9];
    const float* bv   = (const float*)d_in[10];
    const float* Uo   = (const float*)d_in[11];
    const float* Vo   = (const float*)d_in[12];
    const float* bo   = (const float*)d_in[13];
    const float* g1   = (const float*)d_in[14];
    const float* be1  = (const float*)d_in[15];
    const float* U1   = (const float*)d_in[16];
    const float* V1   = (const float*)d_in[17];
    const float* b1   = (const float*)d_in[18];
    const float* U2   = (const float*)d_in[19];
    const float* V2   = (const float*)d_in[20];
    const float* b2   = (const float*)d_in[21];
    const float* g2   = (const float*)d_in[22];
    const float* be2  = (const float*)d_in[23];
    float* out = (float*)d_out;

    const size_t MB = 1048576;
    char* ws = (char*)d_ws;
    u16* Pt  = (u16*)(ws + 0);                 // 3 MB (1536 x 1024 bf16)
    u16* Ftq = (u16*)(ws + 3 * MB);
    u16* Ftk = (u16*)(ws + 3 * MB + 131072);
    u16* Ftv = (u16*)(ws + 3 * MB + 262144);
    u16* Uot = (u16*)(ws + 4 * MB);            // 1 MB (512 x 1024)
    u16* Vot = (u16*)(ws + 5 * MB);            // 1 MB (1024 x 512)
    u16* U1t = (u16*)(ws + 6 * MB);            // 1 MB (512 x 1024)
    u16* V1t = (u16*)(ws + 7 * MB);            // 4 MB (4096 x 512)
    u16* U2t = (u16*)(ws + 11 * MB);           // 4 MB (512 x 4096)
    u16* V2t = (u16*)(ws + 15 * MB);           // 1 MB (1024 x 512)
    u16* Xb  = (u16*)(ws + 16 * MB);           // 16 MB (x bf16; later x1 bf16)
    u16* Tmp = (u16*)(ws + 32 * MB);           // 24 MB (8192 x 1536 bf16)
    u16* Qb  = (u16*)(ws + 56 * MB);           // 16 MB
    u16* Kb  = (u16*)(ws + 72 * MB);           // 16 MB
    u16* Vb  = (u16*)(ws + 88 * MB);           // 16 MB
    u16* Ob  = (u16*)(ws + 104 * MB);          // 16 MB
    u16* Hb  = (u16*)(ws + 32 * MB);           // 64 MB (reuses Tmp/Q/K/V)
    float* Yf = (float*)(ws + 56 * MB);        // 32 MB
    u16* Tb  = (u16*)(ws + 96 * MB);           // 8 MB (8192 x 512 bf16)
    float* X1f = (float*)(ws + 120 * MB);      // 32 MB ; end = 152 MB

    // --- all precompute in one launch ---
    prep_all<<<4016, 256, 0, stream>>>(x, Pq, Pk, Pv, Vq, Vk, Vv,
                                       Uo, Vo, U1, V1, U2, V2,
                                       Xb, Pt, Ftq, Ftk, Ftv,
                                       Uot, Vot, U1t, V1t, U2t, V2t);

    // --- QKV ---
    gemm_bf16<0, 4><<<dim3(12, 64), 256, 0, stream>>>(Xb, Pt, nullptr, Tmp, 1024, 1536);
    qkv_s2<<<dim3(128, 16), 256, 0, stream>>>(Tmp, Ftq, Ftk, Ftv, bq, bk, bv, Qb, Kb, Vb);

    // --- attention ---
    attn_mfma<<<2048, 256, 0, stream>>>(Qb, Kb, Vb, mask, Ob);

    // --- attn out proj + LN1 ---
    gemm_db<<<dim3(8, 64), 256, 0, stream>>>(Ob, Uot, Tb, 1024, 512);
    gemm_bf16<3, 4><<<dim3(8, 64), 256, 0, stream>>>(Tb, Vot, nullptr, Yf, 512, 1024);
    ln_kernel<true><<<8192, 256, 0, stream>>>(Yf, x, bo, g1, be1, X1f, Xb);

    // --- FFN + LN2 ---
    gemm_db<<<dim3(8, 64), 256, 0, stream>>>(Xb, U1t, Tb, 1024, 512);
    gemm_bf16<2, 4><<<dim3(32, 64), 256, 0, stream>>>(Tb, V1t, b1, Hb, 512, 4096);
    gemm_db<<<dim3(8, 64), 256, 0, stream>>>(Hb, U2t, Tb, 4096, 512);
    gemm_bf16<3, 4><<<dim3(8, 64), 256, 0, stream>>>(Tb, V2t, nullptr, Yf, 512, 1024);
    ln_kernel<false><<<8192, 256, 0, stream>>>(Yf, X1f, b2, g2, be2, out, nullptr);
}

// Round 6
// 335.467 us; speedup vs baseline: 12.4712x; 1.0357x over previous
//
#include <hip/hip_runtime.h>
#include <hip/hip_bf16.h>
#include <math.h>

typedef unsigned short u16;
typedef unsigned int u32;
typedef __attribute__((ext_vector_type(8))) short bf16x8;
typedef __attribute__((ext_vector_type(4))) float f32x4;
typedef __attribute__((ext_vector_type(2))) unsigned int u32x2;
typedef __attribute__((ext_vector_type(4))) unsigned int u32x4;

#define B_ 8
#define M_ 1024
#define DM_ 1024
#define H_ 16
#define DH_ 64
#define NR_ 8192

__device__ __forceinline__ u16 f2bf(float f) {
    unsigned u = __float_as_uint(f);
    u += 0x7FFFu + ((u >> 16) & 1u);
    return (u16)(u >> 16);
}

__device__ __forceinline__ void gload16(const void* g, void* l) {
    __builtin_amdgcn_global_load_lds(
        (const __attribute__((address_space(1))) void*)g,
        (__attribute__((address_space(3))) void*)l, 16, 0, 0);
}

__device__ __forceinline__ u32 lds_addr(const void* p) {
    return (u32)(uintptr_t)(const __attribute__((address_space(3))) void*)p;
}

// ---------------------------------------------------------------------------
// Mega-prep: x->bf16, P transposes, V-factor transposes, 6 weight transposes.
// ---------------------------------------------------------------------------
__device__ void conv_dev(const float* __restrict__ in, u16* __restrict__ out,
                         int bid, int tid) {
#pragma unroll
    for (int j = 0; j < 4; ++j) {
        int i = bid * 4096 + j * 1024 + tid * 4;
        float4 v = *reinterpret_cast<const float4*>(in + i);
        unsigned long long p = (unsigned long long)f2bf(v.x)
                             | ((unsigned long long)f2bf(v.y) << 16)
                             | ((unsigned long long)f2bf(v.z) << 32)
                             | ((unsigned long long)f2bf(v.w) << 48);
        *reinterpret_cast<unsigned long long*>(out + i) = p;
    }
}

__device__ void prep_p_dev(const float* __restrict__ P, u16* __restrict__ Pt,
                           int h, int kc, int tid, float* sm) {
    float (*Ps)[33] = (float(*)[33])sm;
#pragma unroll
    for (int i = 0; i < 16; ++i) {
        int e = tid + i * 256;
        int kk = e >> 5, r = e & 31;
        Ps[kk][r] = P[(size_t)h * 32768 + (size_t)(kc + kk) * 32 + r];
    }
    __syncthreads();
#pragma unroll
    for (int i = 0; i < 16; ++i) {
        int e = tid + i * 256;
        int r = e >> 7, k = e & 127;
        Pt[(size_t)(h * 32 + r) * 1024 + kc + k] = f2bf(Ps[k][r]);
    }
}

__device__ void prep_f_dev(const float* __restrict__ V, u16* __restrict__ Ft,
                           int h, int tid, float* sm) {
    float (*Vs)[65] = (float(*)[65])sm;
#pragma unroll
    for (int i = 0; i < 8; ++i) {
        int e = tid + i * 256;
        int r = e >> 6, c = e & 63;
        Vs[r][c] = V[(size_t)h * 2048 + r * 64 + c];
    }
    __syncthreads();
#pragma unroll
    for (int i = 0; i < 8; ++i) {
        int idx = tid + i * 256;
        int e = idx >> 5, r = idx & 31;
        Ft[(size_t)h * 2560 + e * 40 + r] = f2bf(Vs[r][e]);
    }
}

__device__ void transp_dev(const float* __restrict__ in, u16* __restrict__ out,
                           int R, int C, int bx, int by, int tid, float* sm) {
    float (*t)[65] = (float(*)[65])sm;
    const int rb = by * 64, cb = bx * 64;
#pragma unroll
    for (int i = 0; i < 16; ++i) {
        int e = tid + i * 256;
        int r = e >> 6, c = e & 63;
        t[r][c] = in[(size_t)(rb + r) * C + cb + c];
    }
    __syncthreads();
#pragma unroll
    for (int i = 0; i < 16; ++i) {
        int e = tid + i * 256;
        int r = e >> 6, c = e & 63;
        out[(size_t)(cb + r) * R + rb + c] = f2bf(t[c][r]);
    }
}

__global__ __launch_bounds__(256) void prep_all(
    const float* __restrict__ x,
    const float* __restrict__ Pq, const float* __restrict__ Pk, const float* __restrict__ Pv,
    const float* __restrict__ Vq, const float* __restrict__ Vk, const float* __restrict__ Vv,
    const float* __restrict__ Uo, const float* __restrict__ Vo,
    const float* __restrict__ U1, const float* __restrict__ V1,
    const float* __restrict__ U2, const float* __restrict__ V2,
    u16* __restrict__ Xb, u16* __restrict__ Pt,
    u16* __restrict__ Ftq, u16* __restrict__ Ftk, u16* __restrict__ Ftv,
    u16* __restrict__ Uot, u16* __restrict__ Vot,
    u16* __restrict__ U1t, u16* __restrict__ V1t,
    u16* __restrict__ U2t, u16* __restrict__ V2t) {
    __shared__ float smem[4224];
    const int bid = blockIdx.x, tid = threadIdx.x;
    if (bid < 2048) {
        conv_dev(x, Xb, bid, tid);
    } else if (bid < 2432) {
        int t = bid - 2048, which = t >> 7, tt = t & 127;
        const float* P = which == 0 ? Pq : (which == 1 ? Pk : Pv);
        prep_p_dev(P, Pt + (size_t)which * 524288, tt >> 3, (tt & 7) * 128, tid, smem);
    } else if (bid < 2480) {
        int t = bid - 2432, which = t >> 4;
        const float* V = which == 0 ? Vq : (which == 1 ? Vk : Vv);
        u16* F = which == 0 ? Ftq : (which == 1 ? Ftk : Ftv);
        prep_f_dev(V, F, t & 15, tid, smem);
    } else if (bid < 2608) {
        int t = bid - 2480;
        transp_dev(Uo, Uot, 1024, 512, t & 7, t >> 3, tid, smem);
    } else if (bid < 2736) {
        int t = bid - 2608;
        transp_dev(Vo, Vot, 512, 1024, t & 15, t >> 4, tid, smem);
    } else if (bid < 2864) {
        int t = bid - 2736;
        transp_dev(U1, U1t, 1024, 512, t & 7, t >> 3, tid, smem);
    } else if (bid < 3376) {
        int t = bid - 2864;
        transp_dev(V1, V1t, 512, 4096, t & 63, t >> 6, tid, smem);
    } else if (bid < 3888) {
        int t = bid - 3376;
        transp_dev(U2, U2t, 4096, 512, t & 7, t >> 3, tid, smem);
    } else {
        int t = bid - 3888;
        transp_dev(V2, V2t, 512, 1024, t & 15, t >> 4, tid, smem);
    }
}

// ---------------------------------------------------------------------------
// bf16 MFMA GEMM (single-buffer): C(8192 x N) = A(8192 x K) @ Bt(N x K)^T
// EPI: 2 bias+gelu bf16, 3 f32.
// ---------------------------------------------------------------------------
template <int EPI, int NF>
__global__ __launch_bounds__(256) void gemm_bf16(const u16* __restrict__ A,
                                                 const u16* __restrict__ Bt,
                                                 const float* __restrict__ bias,
                                                 void* __restrict__ Cout,
                                                 int K, int N) {
    constexpr int BN = NF * 32;
    __shared__ u16 As[128 * 64];
    __shared__ u16 Bs[BN * 64];
    const int tid = threadIdx.x;
    const int lane = tid & 63, wv = tid >> 6;

    const int NX = gridDim.x;
    const int flat = blockIdx.x + blockIdx.y * NX;
    const int q = (NX * gridDim.y) >> 3;
    const int nid = (flat & 7) * q + (flat >> 3);
    const int row0 = (nid / NX) * 128, col0 = (nid % NX) * BN;

    const int frow = lane & 15, fk8 = lane >> 4;
    const int wm = (wv >> 1) * 64, wn = (wv & 1) * (BN / 2);

    f32x4 acc[4][NF];
    const f32x4 z4 = {0.f, 0.f, 0.f, 0.f};
#pragma unroll
    for (int i = 0; i < 4; ++i)
#pragma unroll
        for (int j = 0; j < NF; ++j) acc[i][j] = z4;

    for (int k0 = 0; k0 < K; k0 += 64) {
#pragma unroll
        for (int i = 0; i < 4; ++i) {
            int rr = (i * 4 + wv) * 8 + (lane >> 3);
            int cc = ((lane & 7) ^ (rr & 7)) * 8;
            gload16(A + (size_t)(row0 + rr) * K + k0 + cc,
                    (char*)As + (i * 4 + wv) * 1024);
        }
#pragma unroll
        for (int i = 0; i < NF; ++i) {
            int rr = (i * 4 + wv) * 8 + (lane >> 3);
            int cc = ((lane & 7) ^ (rr & 7)) * 8;
            gload16(Bt + (size_t)(col0 + rr) * K + k0 + cc,
                    (char*)Bs + (i * 4 + wv) * 1024);
        }
        asm volatile("s_waitcnt vmcnt(0)" ::: "memory");
        __syncthreads();
#pragma unroll
        for (int kf = 0; kf < 2; ++kf) {
            bf16x8 af[4], bfr[NF];
#pragma unroll
            for (int mf = 0; mf < 4; ++mf) {
                int r = wm + mf * 16 + frow;
                int c16 = (kf * 4 + fk8) ^ (r & 7);
                af[mf] = *reinterpret_cast<const bf16x8*>((char*)As + r * 128 + c16 * 16);
            }
#pragma unroll
            for (int nf = 0; nf < NF; ++nf) {
                int r = wn + nf * 16 + frow;
                int c16 = (kf * 4 + fk8) ^ (r & 7);
                bfr[nf] = *reinterpret_cast<const bf16x8*>((char*)Bs + r * 128 + c16 * 16);
            }
#pragma unroll
            for (int mf = 0; mf < 4; ++mf)
#pragma unroll
                for (int nf = 0; nf < NF; ++nf)
                    acc[mf][nf] = __builtin_amdgcn_mfma_f32_16x16x32_bf16(
                        af[mf], bfr[nf], acc[mf][nf], 0, 0, 0);
        }
        __syncthreads();
    }

    const int orow = fk8 * 4, ocol = frow;
#pragma unroll
    for (int mf = 0; mf < 4; ++mf)
#pragma unroll
        for (int nf = 0; nf < NF; ++nf)
#pragma unroll
            for (int j = 0; j < 4; ++j) {
                int row = row0 + wm + mf * 16 + orow + j;
                int col = col0 + wn + nf * 16 + ocol;
                float v = acc[mf][nf][j];
                if (EPI == 2) {
                    v += bias[col];
                    v = 0.5f * v * (1.f + erff(v * 0.70710678118f));
                    ((u16*)Cout)[(size_t)row * N + col] = f2bf(v);
                } else if (EPI == 3) {
                    ((float*)Cout)[(size_t)row * N + col] = v;
                } else {
                    ((u16*)Cout)[(size_t)row * N + col] = f2bf(v);
                }
            }
}

// ---------------------------------------------------------------------------
// QKV fused GEMM: Tmp-tile = Xb(8192x1024) @ Pt(1536x1024)^T kept in regs,
// then per-head rank-32 transform (x Ft^T) in the epilogue via LDS transpose,
// writing Q/K/V (+bias) directly in (B*H, M, 64) layout.
// grid (12, 64), BN=128.
// ---------------------------------------------------------------------------
__global__ __launch_bounds__(256) void gemm_qkv(const u16* __restrict__ A,
                                                const u16* __restrict__ Bt,
                                                const u16* __restrict__ Ftq,
                                                const u16* __restrict__ Ftk,
                                                const u16* __restrict__ Ftv,
                                                const float* __restrict__ bq,
                                                const float* __restrict__ bk,
                                                const float* __restrict__ bv,
                                                u16* __restrict__ Qo,
                                                u16* __restrict__ Ko,
                                                u16* __restrict__ Vo) {
    const int K = 1024;
    __shared__ u16 As[128 * 64];
    __shared__ u16 Bs[128 * 64];
    const int tid = threadIdx.x;
    const int lane = tid & 63, wv = tid >> 6;

    const int NX = gridDim.x;
    const int flat = blockIdx.x + blockIdx.y * NX;
    const int q = (NX * gridDim.y) >> 3;
    const int nid = (flat & 7) * q + (flat >> 3);
    const int row0 = (nid / NX) * 128, col0 = (nid % NX) * 128;

    const int frow = lane & 15, fk8 = lane >> 4;
    const int wm = (wv >> 1) * 64, wn = (wv & 1) * 64;

    f32x4 acc[4][4];
    const f32x4 z4 = {0.f, 0.f, 0.f, 0.f};
#pragma unroll
    for (int i = 0; i < 4; ++i)
#pragma unroll
        for (int j = 0; j < 4; ++j) acc[i][j] = z4;

    for (int k0 = 0; k0 < K; k0 += 64) {
#pragma unroll
        for (int i = 0; i < 4; ++i) {
            int rr = (i * 4 + wv) * 8 + (lane >> 3);
            int cc = ((lane & 7) ^ (rr & 7)) * 8;
            gload16(A + (size_t)(row0 + rr) * K + k0 + cc,
                    (char*)As + (i * 4 + wv) * 1024);
            gload16(Bt + (size_t)(col0 + rr) * K + k0 + cc,
                    (char*)Bs + (i * 4 + wv) * 1024);
        }
        asm volatile("s_waitcnt vmcnt(0)" ::: "memory");
        __syncthreads();
#pragma unroll
        for (int kf = 0; kf < 2; ++kf) {
            bf16x8 af[4], bfr[4];
#pragma unroll
            for (int mf = 0; mf < 4; ++mf) {
                int r = wm + mf * 16 + frow;
                int c16 = (kf * 4 + fk8) ^ (r & 7);
                af[mf] = *reinterpret_cast<const bf16x8*>((char*)As + r * 128 + c16 * 16);
            }
#pragma unroll
            for (int nf = 0; nf < 4; ++nf) {
                int r = wn + nf * 16 + frow;
                int c16 = (kf * 4 + fk8) ^ (r & 7);
                bfr[nf] = *reinterpret_cast<const bf16x8*>((char*)Bs + r * 128 + c16 * 16);
            }
#pragma unroll
            for (int mf = 0; mf < 4; ++mf)
#pragma unroll
                for (int nf = 0; nf < 4; ++nf)
                    acc[mf][nf] = __builtin_amdgcn_mfma_f32_16x16x32_bf16(
                        af[mf], bfr[nf], acc[mf][nf], 0, 0, 0);
        }
        __syncthreads();
    }

    // --- epilogue: per-head rank-32 transform -------------------------------
    // wave-local 64x64 P-part tile -> own LDS region (XOR-swizzled bf16)
    u16* preg = (wv < 2) ? As + wv * 4096 : Bs + (wv - 2) * 4096;
#pragma unroll
    for (int mf = 0; mf < 4; ++mf)
#pragma unroll
        for (int nf = 0; nf < 4; ++nf)
#pragma unroll
            for (int j = 0; j < 4; ++j) {
                int r = mf * 16 + fk8 * 4 + j;
                int c = nf * 16 + frow;
                int byte = r * 128 + (((c >> 3) ^ (r & 7)) * 16) + (c & 7) * 2;
                *(u16*)((char*)preg + byte) = f2bf(acc[mf][nf][j]);
            }
    __syncthreads();

    const int f = col0 >> 9;                       // 0=q, 1=k, 2=v
    const u16* Ft = f == 0 ? Ftq : (f == 1 ? Ftk : Ftv);
    const float* bias = f == 0 ? bq : (f == 1 ? bk : bv);
    u16* outp = f == 0 ? Qo : (f == 1 ? Ko : Vo);
    const int h0 = (((col0 & 511) + wn) >> 5);     // first of wave's 2 heads

#pragma unroll
    for (int hh = 0; hh < 2; ++hh) {
        const int h = h0 + hh;
        const u16* ftb = Ft + (size_t)h * 2560;
        bf16x8 bf2[4];
#pragma unroll
        for (int ef = 0; ef < 4; ++ef) {
            int e = ef * 16 + frow;
            bf2[ef] = *reinterpret_cast<const bf16x8*>(ftb + e * 40 + fk8 * 8);
        }
#pragma unroll
        for (int mf = 0; mf < 4; ++mf) {
            int r = mf * 16 + frow;
            bf16x8 af = *reinterpret_cast<const bf16x8*>(
                (char*)preg + r * 128 + (((hh * 4 + fk8) ^ (r & 7)) * 16));
#pragma unroll
            for (int ef = 0; ef < 4; ++ef) {
                f32x4 o = __builtin_amdgcn_mfma_f32_16x16x32_bf16(af, bf2[ef], z4, 0, 0, 0);
                int e = ef * 16 + frow;
                float bv_ = bias[h * 64 + e];
#pragma unroll
                for (int j = 0; j < 4; ++j) {
                    int row = row0 + wm + mf * 16 + fk8 * 4 + j;
                    int bb = row >> 10, m = row & 1023;
                    outp[(((size_t)(bb * 16 + h) << 10) + m) * 64 + e] = f2bf(o[j] + bv_);
                }
            }
        }
    }
}

// ---------------------------------------------------------------------------
// Double-buffered prefetch GEMM for N=512 outputs (BN=64, bf16 out).
// ---------------------------------------------------------------------------
__global__ __launch_bounds__(256) void gemm_db(const u16* __restrict__ A,
                                               const u16* __restrict__ Bt,
                                               u16* __restrict__ Cout,
                                               int K, int N) {
    __shared__ u16 As[2][128 * 64];
    __shared__ u16 Bs[2][64 * 64];
    const int tid = threadIdx.x;
    const int lane = tid & 63, wv = tid >> 6;

    const int NX = gridDim.x;
    const int flat = blockIdx.x + blockIdx.y * NX;
    const int q = (NX * gridDim.y) >> 3;
    const int nid = (flat & 7) * q + (flat >> 3);
    const int row0 = (nid / NX) * 128, col0 = (nid % NX) * 64;

    const int frow = lane & 15, fk8 = lane >> 4;
    const int wm = (wv >> 1) * 64, wn = (wv & 1) * 32;

    f32x4 acc[4][2];
    const f32x4 z4 = {0.f, 0.f, 0.f, 0.f};
#pragma unroll
    for (int i = 0; i < 4; ++i) {
        acc[i][0] = z4;
        acc[i][1] = z4;
    }

    const int srr = (lane >> 3);
    const int scc = (lane & 7);

#pragma unroll
    for (int i = 0; i < 4; ++i) {
        int rr = (i * 4 + wv) * 8 + srr;
        int cc = (scc ^ (rr & 7)) * 8;
        gload16(A + (size_t)(row0 + rr) * K + cc, (char*)&As[0][0] + (i * 4 + wv) * 1024);
    }
#pragma unroll
    for (int i = 0; i < 2; ++i) {
        int rr = (i * 4 + wv) * 8 + srr;
        int cc = (scc ^ (rr & 7)) * 8;
        gload16(Bt + (size_t)(col0 + rr) * K + cc, (char*)&Bs[0][0] + (i * 4 + wv) * 1024);
    }

    int cur = 0;
    for (int k0 = 0; k0 < K; k0 += 64) {
        __syncthreads();
        if (k0 + 64 < K) {
            int kn = k0 + 64;
#pragma unroll
            for (int i = 0; i < 4; ++i) {
                int rr = (i * 4 + wv) * 8 + srr;
                int cc = (scc ^ (rr & 7)) * 8;
                gload16(A + (size_t)(row0 + rr) * K + kn + cc,
                        (char*)&As[cur ^ 1][0] + (i * 4 + wv) * 1024);
            }
#pragma unroll
            for (int i = 0; i < 2; ++i) {
                int rr = (i * 4 + wv) * 8 + srr;
                int cc = (scc ^ (rr & 7)) * 8;
                gload16(Bt + (size_t)(col0 + rr) * K + kn + cc,
                        (char*)&Bs[cur ^ 1][0] + (i * 4 + wv) * 1024);
            }
        }
#pragma unroll
        for (int kf = 0; kf < 2; ++kf) {
            bf16x8 af[4], bfr[2];
#pragma unroll
            for (int mf = 0; mf < 4; ++mf) {
                int r = wm + mf * 16 + frow;
                int c16 = (kf * 4 + fk8) ^ (r & 7);
                af[mf] = *reinterpret_cast<const bf16x8*>((char*)&As[cur][0] + r * 128 + c16 * 16);
            }
#pragma unroll
            for (int nf = 0; nf < 2; ++nf) {
                int r = wn + nf * 16 + frow;
                int c16 = (kf * 4 + fk8) ^ (r & 7);
                bfr[nf] = *reinterpret_cast<const bf16x8*>((char*)&Bs[cur][0] + r * 128 + c16 * 16);
            }
#pragma unroll
            for (int mf = 0; mf < 4; ++mf)
#pragma unroll
                for (int nf = 0; nf < 2; ++nf)
                    acc[mf][nf] = __builtin_amdgcn_mfma_f32_16x16x32_bf16(
                        af[mf], bfr[nf], acc[mf][nf], 0, 0, 0);
        }
        cur ^= 1;
    }

#pragma unroll
    for (int mf = 0; mf < 4; ++mf)
#pragma unroll
        for (int nf = 0; nf < 2; ++nf)
#pragma unroll
            for (int j = 0; j < 4; ++j) {
                int row = row0 + wm + mf * 16 + fk8 * 4 + j;
                int col = col0 + wn + nf * 16 + frow;
                Cout[(size_t)row * N + col] = f2bf(acc[mf][nf][j]);
            }
}

// ---------------------------------------------------------------------------
// MFMA flash attention, one-barrier double-buffered K/V pipeline.
// Swapped QK^T, base-2 softmax + defer-max, XOR-swizzled P, tr_read V.
// grid 2048 (XCD remap), 4 waves.  LDS 40 KB -> 4 blocks/CU.
// ---------------------------------------------------------------------------
__global__ __launch_bounds__(256) void attn_mfma(const u16* __restrict__ Q,
                                                 const u16* __restrict__ K,
                                                 const u16* __restrict__ V,
                                                 const float* __restrict__ mask,
                                                 u16* __restrict__ O) {
    __shared__ u16 Ks[2][4096];
    __shared__ u16 Vt[2][4096];
    __shared__ u16 Pw[4096];
    const int flat = blockIdx.x;
    const int nid = (flat & 7) * 256 + (flat >> 3);
    const int hb = nid >> 4, qt = nid & 15;
    const int b = hb >> 4, h = hb & 15;
    const int tid = threadIdx.x, lane = tid & 63, wv = tid >> 6;
    const int frow = lane & 15, fk8 = lane >> 4;
    const size_t base = (size_t)hb * 65536;
    const float LOG2E = 1.44269504089f;
    const int srr = lane >> 3, scc = lane & 7;

    // V staging source offsets (linear subtiled dest -> scattered src)
    int voff[2];
#pragma unroll
    for (int i = 0; i < 2; ++i) {
        int c = (i * 4 + wv) * 64 + lane;
        int kb = c >> 5, db = (c >> 3) & 3, kr = (c >> 1) & 3, hf = c & 1;
        voff[i] = (kb * 4 + kr) * 64 + db * 16 + hf * 8;
    }

    // --- prologue: Q -> Pw, K/V tile0 -> buf0 ---
#pragma unroll
    for (int i = 0; i < 2; ++i) {
        int rr = (i * 4 + wv) * 8 + srr;
        int cc = (scc ^ (rr & 7)) * 8;
        gload16(Q + base + (size_t)(qt * 64 + rr) * 64 + cc,
                (char*)Pw + (i * 4 + wv) * 1024);
        gload16(K + base + (size_t)rr * 64 + cc,
                (char*)&Ks[0][0] + (i * 4 + wv) * 1024);
    }
#pragma unroll
    for (int i = 0; i < 2; ++i)
        gload16(V + base + voff[i], (char*)&Vt[0][0] + (i * 4 + wv) * 1024);
    asm volatile("s_waitcnt vmcnt(0)" ::: "memory");
    __syncthreads();

    // hoist Q fragments (consumed by tile-0 MFMA before first P-write)
    bf16x8 qfrag[2];
#pragma unroll
    for (int kf = 0; kf < 2; ++kf) {
        int qr = wv * 16 + frow;
        int c16 = (kf * 4 + fk8) ^ (qr & 7);
        qfrag[kf] = *reinterpret_cast<const bf16x8*>((char*)Pw + qr * 128 + c16 * 16);
    }

    // tr-read per-lane base addrs (buf0)
    u32 vta[4];
    {
        u32 vt0 = lds_addr(&Vt[0][0]) + fk8 * 1024 + frow * 2;
#pragma unroll
        for (int nf = 0; nf < 4; ++nf) vta[nf] = vt0 + nf * 128;
    }

    char* pwW = (char*)Pw + wv * 2048 + frow * 128 + (fk8 & 1) * 8;
    char* pwR = (char*)Pw + wv * 2048 + frow * 128;
    const float* mrow = mask + b * M_;

    float m_i = -1e30f, l_i = 0.f;
    const f32x4 z4 = {0.f, 0.f, 0.f, 0.f};
    f32x4 o_acc[4] = {z4, z4, z4, z4};

    int cur = 0;
    for (int kt = 0; kt < 16; ++kt) {
        // issue next tile's staging first (latency hides under compute)
        if (kt < 15) {
            const int nxt = cur ^ 1;
#pragma unroll
            for (int i = 0; i < 2; ++i) {
                int rr = (i * 4 + wv) * 8 + srr;
                int cc = (scc ^ (rr & 7)) * 8;
                gload16(K + base + (kt + 1) * 4096 + (size_t)rr * 64 + cc,
                        (char*)&Ks[nxt][0] + (i * 4 + wv) * 1024);
            }
#pragma unroll
            for (int i = 0; i < 2; ++i)
                gload16(V + base + (kt + 1) * 4096 + voff[i],
                        (char*)&Vt[nxt][0] + (i * 4 + wv) * 1024);
        }

        const char* ksb = (char*)&Ks[cur][0];
        const u32 vbo = (u32)(cur * 8192);

        // S^T = K . Q^T : lane holds S[q=frow][key = nf*16 + fk8*4 + j]
        f32x4 sacc[4] = {z4, z4, z4, z4};
        __builtin_amdgcn_s_setprio(1);
#pragma unroll
        for (int kf = 0; kf < 2; ++kf)
#pragma unroll
            for (int nf = 0; nf < 4; ++nf) {
                int kr = nf * 16 + frow;
                int c16 = (kf * 4 + fk8) ^ (kr & 7);
                bf16x8 ak = *reinterpret_cast<const bf16x8*>(ksb + kr * 128 + c16 * 16);
                sacc[nf] = __builtin_amdgcn_mfma_f32_16x16x32_bf16(ak, qfrag[kf], sacc[nf], 0, 0, 0);
            }
        __builtin_amdgcn_s_setprio(0);

        float tval[4][4];
        float tmax = -1e30f;
#pragma unroll
        for (int nf = 0; nf < 4; ++nf) {
            float4 mk = *reinterpret_cast<const float4*>(mrow + kt * 64 + nf * 16 + fk8 * 4);
            float t0 = fmaf(sacc[nf][0], 0.125f, mk.x);
            float t1 = fmaf(sacc[nf][1], 0.125f, mk.y);
            float t2 = fmaf(sacc[nf][2], 0.125f, mk.z);
            float t3 = fmaf(sacc[nf][3], 0.125f, mk.w);
            tval[nf][0] = t0; tval[nf][1] = t1; tval[nf][2] = t2; tval[nf][3] = t3;
            tmax = fmaxf(tmax, fmaxf(fmaxf(t0, t1), fmaxf(t2, t3)));
        }
        tmax = fmaxf(tmax, __shfl_xor(tmax, 16));
        tmax = fmaxf(tmax, __shfl_xor(tmax, 32));

        if (__any(tmax > m_i + 8.f)) {
            float mnew = fmaxf(m_i, tmax);
            float c = exp2f((m_i - mnew) * LOG2E);
            m_i = mnew;
            l_i *= c;
#pragma unroll
            for (int j = 0; j < 4; ++j) {
                float cj = __shfl(c, fk8 * 4 + j);
#pragma unroll
                for (int nf = 0; nf < 4; ++nf) o_acc[nf][j] *= cj;
            }
        }

        const float ml = m_i * LOG2E;
        float rs = 0.f;
#pragma unroll
        for (int nf = 0; nf < 4; ++nf) {
            float p0 = exp2f(fmaf(tval[nf][0], LOG2E, -ml));
            float p1 = exp2f(fmaf(tval[nf][1], LOG2E, -ml));
            float p2 = exp2f(fmaf(tval[nf][2], LOG2E, -ml));
            float p3 = exp2f(fmaf(tval[nf][3], LOG2E, -ml));
            rs += (p0 + p1) + (p2 + p3);
            u32 w0 = __builtin_amdgcn_perm(__float_as_uint(p1), __float_as_uint(p0), 0x07060302u);
            u32 w1 = __builtin_amdgcn_perm(__float_as_uint(p3), __float_as_uint(p2), 0x07060302u);
            u32x2 wp = {w0, w1};
            *reinterpret_cast<u32x2*>(pwW + (((nf * 2 + (fk8 >> 1)) ^ (frow & 7)) * 16)) = wp;
        }
        rs += __shfl_xor(rs, 16);
        rs += __shfl_xor(rs, 32);
        l_i += rs;

        // O += P @ V  (A = P rows from swizzled LDS, B = V via tr-reads)
#pragma unroll
        for (int kf = 0; kf < 2; ++kf) {
            bf16x8 ap = *reinterpret_cast<const bf16x8*>(pwR + (((kf * 4 + fk8) ^ (frow & 7)) * 16));
            u32 a0 = vta[0] + vbo, a1 = vta[1] + vbo, a2 = vta[2] + vbo, a3 = vta[3] + vbo;
            u32x2 r0, r1, r2, r3, r4, r5, r6, r7;
            if (kf == 0) {
                asm volatile("ds_read_b64_tr_b16 %0, %1" : "=&v"(r0) : "v"(a0));
                asm volatile("ds_read_b64_tr_b16 %0, %1 offset:512" : "=&v"(r1) : "v"(a0));
                asm volatile("ds_read_b64_tr_b16 %0, %1" : "=&v"(r2) : "v"(a1));
                asm volatile("ds_read_b64_tr_b16 %0, %1 offset:512" : "=&v"(r3) : "v"(a1));
                asm volatile("ds_read_b64_tr_b16 %0, %1" : "=&v"(r4) : "v"(a2));
                asm volatile("ds_read_b64_tr_b16 %0, %1 offset:512" : "=&v"(r5) : "v"(a2));
                asm volatile("ds_read_b64_tr_b16 %0, %1" : "=&v"(r6) : "v"(a3));
                asm volatile("ds_read_b64_tr_b16 %0, %1 offset:512" : "=&v"(r7) : "v"(a3));
            } else {
                asm volatile("ds_read_b64_tr_b16 %0, %1 offset:4096" : "=&v"(r0) : "v"(a0));
                asm volatile("ds_read_b64_tr_b16 %0, %1 offset:4608" : "=&v"(r1) : "v"(a0));
                asm volatile("ds_read_b64_tr_b16 %0, %1 offset:4096" : "=&v"(r2) : "v"(a1));
                asm volatile("ds_read_b64_tr_b16 %0, %1 offset:4608" : "=&v"(r3) : "v"(a1));
                asm volatile("ds_read_b64_tr_b16 %0, %1 offset:4096" : "=&v"(r4) : "v"(a2));
                asm volatile("ds_read_b64_tr_b16 %0, %1 offset:4608" : "=&v"(r5) : "v"(a2));
                asm volatile("ds_read_b64_tr_b16 %0, %1 offset:4096" : "=&v"(r6) : "v"(a3));
                asm volatile("ds_read_b64_tr_b16 %0, %1 offset:4608" : "=&v"(r7) : "v"(a3));
            }
            asm volatile("s_waitcnt lgkmcnt(0)" ::: "memory");
            __builtin_amdgcn_sched_barrier(0);
            __builtin_amdgcn_s_setprio(1);
            {
                u32x4 vv = {r0.x, r0.y, r1.x, r1.y};
                bf16x8 fb; __builtin_memcpy(&fb, &vv, 16);
                o_acc[0] = __builtin_amdgcn_mfma_f32_16x16x32_bf16(ap, fb, o_acc[0], 0, 0, 0);
            }
            {
                u32x4 vv = {r2.x, r2.y, r3.x, r3.y};
                bf16x8 fb; __builtin_memcpy(&fb, &vv, 16);
                o_acc[1] = __builtin_amdgcn_mfma_f32_16x16x32_bf16(ap, fb, o_acc[1], 0, 0, 0);
            }
            {
                u32x4 vv = {r4.x, r4.y, r5.x, r5.y};
                bf16x8 fb; __builtin_memcpy(&fb, &vv, 16);
                o_acc[2] = __builtin_amdgcn_mfma_f32_16x16x32_bf16(ap, fb, o_acc[2], 0, 0, 0);
            }
            {
                u32x4 vv = {r6.x, r6.y, r7.x, r7.y};
                bf16x8 fb; __builtin_memcpy(&fb, &vv, 16);
                o_acc[3] = __builtin_amdgcn_mfma_f32_16x16x32_bf16(ap, fb, o_acc[3], 0, 0, 0);
            }
            __builtin_amdgcn_s_setprio(0);
        }

        // drain next-tile staging (was in flight during all of the above)
        asm volatile("s_waitcnt vmcnt(0)" ::: "memory");
        __syncthreads();
        cur ^= 1;
    }

    // epilogue
#pragma unroll
    for (int j = 0; j < 4; ++j) {
        float lq = __shfl(l_i, fk8 * 4 + j);
        float inv = 1.f / lq;
        int grow = qt * 64 + wv * 16 + fk8 * 4 + j;
        size_t obase = ((size_t)(b * M_ + grow)) * DM_ + h * 64;
#pragma unroll
        for (int nf = 0; nf < 4; ++nf)
            O[obase + nf * 16 + frow] = f2bf(o_acc[nf][j] * inv);
    }
}

// ---------------------------------------------------------------------------
// LN: out = LN(y + res + bias) * g + beta ; optional bf16 copy.  1 row/block.
// ---------------------------------------------------------------------------
template <bool WBF>
__global__ __launch_bounds__(256) void ln_kernel(const float* __restrict__ y,
                                                 const float* __restrict__ res,
                                                 const float* __restrict__ bias,
                                                 const float* __restrict__ g,
                                                 const float* __restrict__ beta,
                                                 float* __restrict__ outf,
                                                 u16* __restrict__ outb) {
    __shared__ float red[2][4];
    const int row = blockIdx.x, tid = threadIdx.x;
    const size_t base = (size_t)row * 1024 + tid * 4;
    float4 v = *reinterpret_cast<const float4*>(y + base);
    float4 r = *reinterpret_cast<const float4*>(res + base);
    float4 bb = *reinterpret_cast<const float4*>(bias + tid * 4);
    v.x += r.x + bb.x; v.y += r.y + bb.y; v.z += r.z + bb.z; v.w += r.w + bb.w;
    float sum = v.x + v.y + v.z + v.w;
    float sq = v.x * v.x + v.y * v.y + v.z * v.z + v.w * v.w;
#pragma unroll
    for (int off = 32; off; off >>= 1) {
        sum += __shfl_down(sum, off);
        sq += __shfl_down(sq, off);
    }
    if ((tid & 63) == 0) { red[0][tid >> 6] = sum; red[1][tid >> 6] = sq; }
    __syncthreads();
    sum = red[0][0] + red[0][1] + red[0][2] + red[0][3];
    sq = red[1][0] + red[1][1] + red[1][2] + red[1][3];
    float mu = sum * (1.f / 1024.f);
    float var = sq * (1.f / 1024.f) - mu * mu;
    float rstd = rsqrtf(var + 1e-12f);
    float4 gg = *reinterpret_cast<const float4*>(g + tid * 4);
    float4 be = *reinterpret_cast<const float4*>(beta + tid * 4);
    float4 o;
    o.x = (v.x - mu) * rstd * gg.x + be.x;
    o.y = (v.y - mu) * rstd * gg.y + be.y;
    o.z = (v.z - mu) * rstd * gg.z + be.z;
    o.w = (v.w - mu) * rstd * gg.w + be.w;
    *reinterpret_cast<float4*>(outf + base) = o;
    if (WBF) {
        unsigned long long p = (unsigned long long)f2bf(o.x)
                             | ((unsigned long long)f2bf(o.y) << 16)
                             | ((unsigned long long)f2bf(o.z) << 32)
                             | ((unsigned long long)f2bf(o.w) << 48);
        *reinterpret_cast<unsigned long long*>(outb + base) = p;
    }
}

// ---------------------------------------------------------------------------
extern "C" void kernel_launch(void* const* d_in, const int* in_sizes, int n_in,
                              void* d_out, int out_size, void* d_ws, size_t ws_size,
                              hipStream_t stream) {
    const float* x    = (const float*)d_in[0];
    const float* mask = (const float*)d_in[1];
    const float* Pq   = (const float*)d_in[2];
    const float* Vq   = (const float*)d_in[3];
    const float* bq   = (const float*)d_in[4];
    const float* Pk   = (const float*)d_in[5];
    const float* Vk   = (const float*)d_in[6];
    const float* bk   = (const float*)d_in[7];
    const float* Pv   = (const float*)d_in[8];
    const float* Vv   = (const float*)d_in[9];
    const float* bv   = (const float*)d_in[10];
    const float* Uo   = (const float*)d_in[11];
    const float* Vo   = (const float*)d_in[12];
    const float* bo   = (const float*)d_in[13];
    const float* g1   = (const float*)d_in[14];
    const float* be1  = (const float*)d_in[15];
    const float* U1   = (const float*)d_in[16];
    const float* V1   = (const float*)d_in[17];
    const float* b1   = (const float*)d_in[18];
    const float* U2   = (const float*)d_in[19];
    const float* V2   = (const float*)d_in[20];
    const float* b2   = (const float*)d_in[21];
    const float* g2   = (const float*)d_in[22];
    const float* be2  = (const float*)d_in[23];
    float* out = (float*)d_out;

    const size_t MB = 1048576;
    char* ws = (char*)d_ws;
    u16* Pt  = (u16*)(ws + 0);                 // 3 MB (1536 x 1024 bf16)
    u16* Ftq = (u16*)(ws + 3 * MB);
    u16* Ftk = (u16*)(ws + 3 * MB + 131072);
    u16* Ftv = (u16*)(ws + 3 * MB + 262144);
    u16* Uot = (u16*)(ws + 4 * MB);            // 1 MB (512 x 1024)
    u16* Vot = (u16*)(ws + 5 * MB);            // 1 MB (1024 x 512)
    u16* U1t = (u16*)(ws + 6 * MB);            // 1 MB (512 x 1024)
    u16* V1t = (u16*)(ws + 7 * MB);            // 4 MB (4096 x 512)
    u16* U2t = (u16*)(ws + 11 * MB);           // 4 MB (512 x 4096)
    u16* V2t = (u16*)(ws + 15 * MB);           // 1 MB (1024 x 512)
    u16* Xb  = (u16*)(ws + 16 * MB);           // 16 MB (x bf16; later x1 bf16)
    u16* Qb  = (u16*)(ws + 56 * MB);           // 16 MB
    u16* Kb  = (u16*)(ws + 72 * MB);           // 16 MB
    u16* Vb  = (u16*)(ws + 88 * MB);           // 16 MB
    u16* Ob  = (u16*)(ws + 104 * MB);          // 16 MB
    u16* Hb  = (u16*)(ws + 32 * MB);           // 64 MB (reuses Q/K/V area later)
    float* Yf = (float*)(ws + 56 * MB);        // 32 MB
    u16* Tb  = (u16*)(ws + 96 * MB);           // 8 MB (8192 x 512 bf16)
    float* X1f = (float*)(ws + 120 * MB);      // 32 MB ; end = 152 MB

    // --- all precompute in one launch ---
    prep_all<<<4016, 256, 0, stream>>>(x, Pq, Pk, Pv, Vq, Vk, Vv,
                                       Uo, Vo, U1, V1, U2, V2,
                                       Xb, Pt, Ftq, Ftk, Ftv,
                                       Uot, Vot, U1t, V1t, U2t, V2t);

    // --- QKV: one fused GEMM (stage-1 matmul + per-head rank-32 epilogue) ---
    gemm_qkv<<<dim3(12, 64), 256, 0, stream>>>(Xb, Pt, Ftq, Ftk, Ftv,
                                               bq, bk, bv, Qb, Kb, Vb);

    // --- attention ---
    attn_mfma<<<2048, 256, 0, stream>>>(Qb, Kb, Vb, mask, Ob);

    // --- attn out proj + LN1 ---
    gemm_db<<<dim3(8, 64), 256, 0, stream>>>(Ob, Uot, Tb, 1024, 512);
    gemm_bf16<3, 4><<<dim3(8, 64), 256, 0, stream>>>(Tb, Vot, nullptr, Yf, 512, 1024);
    ln_kernel<true><<<8192, 256, 0, stream>>>(Yf, x, bo, g1, be1, X1f, Xb);

    // --- FFN + LN2 ---
    gemm_db<<<dim3(8, 64), 256, 0, stream>>>(Xb, U1t, Tb, 1024, 512);
    gemm_bf16<2, 4><<<dim3(32, 64), 256, 0, stream>>>(Tb, V1t, b1, Hb, 512, 4096);
    gemm_db<<<dim3(8, 64), 256, 0, stream>>>(Hb, U2t, Tb, 4096, 512);
    gemm_bf16<3, 4><<<dim3(8, 64), 256, 0, stream>>>(Tb, V2t, nullptr, Yf, 512, 1024);
    ln_kernel<false><<<8192, 256, 0, stream>>>(Yf, X1f, b2, g2, be2, out, nullptr);
}